// Round 4
// baseline (89.873 us; speedup 1.0000x reference)
//
#include <hip/hip_runtime.h>

#define BN_EPS 1e-5f

typedef const float* fp;
typedef float f32x4 __attribute__((ext_vector_type(4)));
typedef _Float16 f16x2 __attribute__((ext_vector_type(2)));
typedef _Float16 f16x4 __attribute__((ext_vector_type(4)));
typedef _Float16 f16x8 __attribute__((ext_vector_type(8)));

// fast transcendentals: identical formulas to the previous (passing) kernel.
__device__ __forceinline__ float frcp(float x) { return __builtin_amdgcn_rcpf(x); }
__device__ __forceinline__ float sigm(float x) { return frcp(1.0f + __expf(-x)); }
__device__ __forceinline__ float tanh_fast(float x) { return 1.0f - 2.0f * frcp(1.0f + __expf(2.0f * x)); }

__device__ __forceinline__ f32x4 ld4(const float* p) { return *(const f32x4*)p; }
__device__ __forceinline__ float dot4(f32x4 a, f32x4 b) {
    return a[0] * b[0] + a[1] * b[1] + a[2] * b[2] + a[3] * b[3];
}

#define MFMA16(A, B, C) __builtin_amdgcn_mfma_f32_16x16x16f16((A), (B), (C), 0, 0, 0)
#define MFMA32(A, B, C) __builtin_amdgcn_mfma_f32_16x16x32_f16((A), (B), (C), 0, 0, 0)

// pack f32x4 -> f16x4 via v_cvt_pkrtz. RTZ fine: lo-residual absorbs rounding.
__device__ __forceinline__ f16x4 pk_f16(f32x4 v) {
    f16x2 lo = __builtin_bit_cast(f16x2, __builtin_amdgcn_cvt_pkrtz(v[0], v[1]));
    f16x2 hi = __builtin_bit_cast(f16x2, __builtin_amdgcn_cvt_pkrtz(v[2], v[3]));
    return __builtin_shufflevector(lo, hi, 0, 1, 2, 3);
}

// ---------------------------------------------------------------------------
// K1: fold item/cat embedding tables through Wih; zero the BN stats accums.
// ---------------------------------------------------------------------------
__global__ __launch_bounds__(256) void k_precompute(
    fp Wih, fp bih, fp bhh, fp item_table, fp cat_table,
    float* __restrict__ P_item, float* __restrict__ P_cat,
    float* __restrict__ stats, int nItemElems, int nItemBlocks)
{
    __shared__ float w[768];
    for (int t = threadIdx.x; t < 768; t += blockDim.x) w[t] = Wih[t];
    __syncthreads();

    if ((int)blockIdx.x < nItemBlocks) {
        int idx = blockIdx.x * blockDim.x + threadIdx.x;
        if (idx < nItemElems) {
            int i = idx / 48, g = idx % 48;
            const float* row = item_table + (size_t)i * 12;
            float acc = 0.f;
#pragma unroll
            for (int k = 0; k < 12; ++k) acc += w[g * 16 + k] * row[k];
            P_item[idx] = acc;
        }
    } else {
        for (int t = threadIdx.x; t < 480; t += blockDim.x) {
            int c = t / 48, g = t % 48;
            float acc = bih[g] + (g < 32 ? bhh[g] : 0.f);
#pragma unroll
            for (int k = 0; k < 4; ++k) acc += w[g * 16 + 12 + k] * cat_table[c * 4 + k];
            P_cat[c * 52 + g] = acc;
        }
        if (threadIdx.x < 128) stats[threadIdx.x] = 0.f;   // stats1[96] + stats2[32]
    }
}

// ---------------------------------------------------------------------------
// K2: MFMA GRU, TWO independent chains per wave (32 samples/wave).
// Lane l: sample s=l&15 (within each chain), hi=l>>4. Chain c owns samples
// base + c*16 + s. Weights/A-fragments are lane-layout-only => shared.
// Per gate: MFMA32(A=[W_hi|W_lo], B=[h_hi|h_hi]) in PARALLEL with
// MFMA16(W_hi, h_lo) residual (C=0), merged by a VALU add — no MFMA->MFMA
// serial link. D layout == next B layout: zero cross-lane recurrence.
// ---------------------------------------------------------------------------
__device__ __forceinline__ void gru2(
    const f16x8& wrA, const f16x8& wzA, const f16x8& wnA,
    const f16x4& wrh, const f16x4& wzh, const f16x4& wnh, const f32x4& bhn4,
    f32x4 xr0, f32x4 xz0, f32x4 xn0, f32x4 xr1, f32x4 xz1, f32x4 xn1,
    f32x4& h0, f32x4& hsum0, f16x4& hh0, f16x4& hl0,
    f32x4& h1, f32x4& hsum1, f16x4& hh1, f16x4& hl1)
{
    const f32x4 zero4 = {0.f, 0.f, 0.f, 0.f};
    f16x8 hB0 = __builtin_shufflevector(hh0, hh0, 0, 1, 2, 3, 0, 1, 2, 3);
    f16x8 hB1 = __builtin_shufflevector(hh1, hh1, 0, 1, 2, 3, 0, 1, 2, 3);
    f32x4 aR0 = MFMA32(wrA, hB0, xr0);
    f32x4 aR1 = MFMA32(wrA, hB1, xr1);
    f32x4 aZ0 = MFMA32(wzA, hB0, xz0);
    f32x4 aZ1 = MFMA32(wzA, hB1, xz1);
    f32x4 aN0 = MFMA32(wnA, hB0, bhn4);
    f32x4 aN1 = MFMA32(wnA, hB1, bhn4);
    f32x4 eR0 = MFMA16(wrh, hl0, zero4);
    f32x4 eR1 = MFMA16(wrh, hl1, zero4);
    f32x4 eZ0 = MFMA16(wzh, hl0, zero4);
    f32x4 eZ1 = MFMA16(wzh, hl1, zero4);
    f32x4 eN0 = MFMA16(wnh, hl0, zero4);
    f32x4 eN1 = MFMA16(wnh, hl1, zero4);
#pragma unroll
    for (int q = 0; q < 4; ++q) {
        float r0 = sigm(aR0[q] + eR0[q]);
        float r1 = sigm(aR1[q] + eR1[q]);
        float z0 = sigm(aZ0[q] + eZ0[q]);
        float z1 = sigm(aZ1[q] + eZ1[q]);
        float n0 = tanh_fast(fmaf(r0, aN0[q] + eN0[q], xn0[q]));
        float n1 = tanh_fast(fmaf(r1, aN1[q] + eN1[q], xn1[q]));
        h0[q] = z0 * (h0[q] - n0) + n0;
        h1[q] = z1 * (h1[q] - n1) + n1;
    }
    hsum0 += h0;
    hsum1 += h1;
    hh0 = pk_f16(h0);
    hh1 = pk_f16(h1);
    f32x4 hb0, hb1;
#pragma unroll
    for (int q = 0; q < 4; ++q) { hb0[q] = (float)hh0[q]; hb1[q] = (float)hh1[q]; }
    hl0 = pk_f16(h0 - hb0);
    hl1 = pk_f16(h1 - hb1);
}

// per-chain epilogue: degenerate MHA -> avg, target emb, user emb
__device__ __forceinline__ void epilogue_chain(
    long b, int ti, int tc, int uid, int hi, f32x4 hsum,
    fp item_table, fp cat_table, fp user_table,
    fp mha_Win, fp mha_bin, fp mha_Wout, fp mha_bout,
    f32x4& avg_o, f32x4& t4_o, f32x4& u4_o)
{
    const float* itr = item_table + (size_t)ti * 12;
    f32x4 tv0 = ld4(itr), tv1 = ld4(itr + 4), tv2 = ld4(itr + 8);
    f32x4 tv3 = ld4(cat_table + tc * 4);

    f32x4 vq;
#pragma unroll
    for (int q = 0; q < 4; ++q) {
        int row = 32 + 4 * hi + q;
        const float* wv = mha_Win + row * 16;
        vq[q] = mha_bin[row] + dot4(ld4(wv), tv0) + dot4(ld4(wv + 4), tv1)
              + dot4(ld4(wv + 8), tv2) + dot4(ld4(wv + 12), tv3);
    }
    f32x4 vg0, vg1, vg2, vg3;
#pragma unroll
    for (int q = 0; q < 4; ++q) {
        vg0[q] = __shfl_xor(vq[q], (hi ^ 0) << 4);
        vg1[q] = __shfl_xor(vq[q], (hi ^ 1) << 4);
        vg2[q] = __shfl_xor(vq[q], (hi ^ 2) << 4);
        vg3[q] = __shfl_xor(vq[q], (hi ^ 3) << 4);
    }
    f32x4 aj;
#pragma unroll
    for (int q = 0; q < 4; ++q) {
        int row = 4 * hi + q;
        const float* wo = mha_Wout + row * 16;
        aj[q] = mha_bout[row] + dot4(ld4(wo), vg0) + dot4(ld4(wo + 4), vg1)
              + dot4(ld4(wo + 8), vg2) + dot4(ld4(wo + 12), vg3);
    }
    avg_o = aj * hsum;
    u4_o  = ld4(user_table + (size_t)uid * 16 + 4 * hi);
    t4_o  = (hi == 0) ? tv0 : (hi == 1) ? tv1 : (hi == 2) ? tv2 : tv3;
}

__global__ __launch_bounds__(256, 1) void k_gru(
    const int* __restrict__ user_id, const int* __restrict__ hist_item,
    const int* __restrict__ hist_cat, const int* __restrict__ tgt_item,
    const int* __restrict__ tgt_cat,
    fp user_table, fp item_table, fp cat_table,
    fp Whh, fp bhh,
    fp mha_Win, fp mha_bin, fp mha_Wout, fp mha_bout,
    const float* __restrict__ P_item, const float* __restrict__ P_cat,
    float* __restrict__ all_enc, float* __restrict__ stats1, int B, int T)
{
    __shared__ float s_pcat[520];       // 10 cats x 52 (padded)
    __shared__ float lds_part[4][96];

    const int tid  = threadIdx.x;
    const int lane = tid & 63;
    const int wid  = tid >> 6;
    const int s    = lane & 15;
    const int hi   = lane >> 4;

    long b0 = (long)blockIdx.x * 128 + wid * 32 + s;   // chain 0 sample
    long b1 = b0 + 16;                                 // chain 1 sample
    const bool act0 = (b0 < B), act1 = (b1 < B);
    if (!act0) b0 = B - 1;
    if (!act1) b1 = B - 1;

    for (int t = tid; t < 520; t += 256) s_pcat[t] = P_cat[t];

    // prefetch epilogue indices early
    const int ti0 = tgt_item[b0], tc0 = tgt_cat[b0], uid0 = user_id[b0];
    const int ti1 = tgt_item[b1], tc1 = tgt_cat[b1], uid1 = user_id[b1];

    // Whh A-fragments (shared by both chains; layout depends on lane only)
    f32x4 wrf = ld4(&Whh[(0  + s) * 16 + 4 * hi]);
    f32x4 wzf = ld4(&Whh[(16 + s) * 16 + 4 * hi]);
    f32x4 wnf = ld4(&Whh[(32 + s) * 16 + 4 * hi]);
    f16x4 wrh = __builtin_convertvector(wrf, f16x4);
    f16x4 wzh = __builtin_convertvector(wzf, f16x4);
    f16x4 wnh = __builtin_convertvector(wnf, f16x4);
    f16x4 wrl = __builtin_convertvector(wrf - __builtin_convertvector(wrh, f32x4), f16x4);
    f16x4 wzl = __builtin_convertvector(wzf - __builtin_convertvector(wzh, f32x4), f16x4);
    f16x4 wnl = __builtin_convertvector(wnf - __builtin_convertvector(wnh, f32x4), f16x4);
    f16x8 wrA = __builtin_shufflevector(wrh, wrl, 0, 1, 2, 3, 4, 5, 6, 7);
    f16x8 wzA = __builtin_shufflevector(wzh, wzl, 0, 1, 2, 3, 4, 5, 6, 7);
    f16x8 wnA = __builtin_shufflevector(wnh, wnl, 0, 1, 2, 3, 4, 5, 6, 7);
    const f32x4 bhn4 = ld4(&bhh[32 + 4 * hi]);

    const int* ip0 = hist_item + b0 * T;
    const int* cp0 = hist_cat  + b0 * T;
    const int* ip1 = hist_item + b1 * T;
    const int* cp1 = hist_cat  + b1 * T;

    f32x4 h0 = {0.f,0.f,0.f,0.f}, hsum0 = {0.f,0.f,0.f,0.f};
    f32x4 h1 = {0.f,0.f,0.f,0.f}, hsum1 = {0.f,0.f,0.f,0.f};
    f16x4 hh0 = {}, hl0 = {}, hh1 = {}, hl1 = {};

    __syncthreads();   // s_pcat ready

    // prefetch register sets: [chain][parity A=even step, B=odd step]
    f32x4 pirA0, pizA0, pinA0, pcrA0, pczA0, pcnA0;
    f32x4 pirB0, pizB0, pinB0, pcrB0, pczB0, pcnB0;
    f32x4 pirA1, pizA1, pinA1, pcrA1, pczA1, pcnA1;
    f32x4 pirB1, pizB1, pinB1, pcrB1, pczB1, pcnB1;

#define ISSUE_LD(SUF, idv, cdv) do { \
    const float* pi_ = P_item + (unsigned)(idv) * 48u; int pb_ = (cdv) * 52; \
    pir##SUF = ld4(pi_ + 4 * hi); piz##SUF = ld4(pi_ + 16 + 4 * hi); pin##SUF = ld4(pi_ + 32 + 4 * hi); \
    pcr##SUF = ld4(&s_pcat[pb_ + 4 * hi]); pcz##SUF = ld4(&s_pcat[pb_ + 16 + 4 * hi]); \
    pcn##SUF = ld4(&s_pcat[pb_ + 32 + 4 * hi]); } while (0)

    const int tl = T - 1;
    int idA0 = ip0[0], cdA0 = cp0[0], idA1 = ip1[0], cdA1 = cp1[0];
    ISSUE_LD(A0, idA0, cdA0);
    ISSUE_LD(A1, idA1, cdA1);
    int i1 = (1 <= tl) ? 1 : tl;
    int idB0 = ip0[i1], cdB0 = cp0[i1], idB1 = ip1[i1], cdB1 = cp1[i1];
    ISSUE_LD(B0, idB0, cdB0);
    ISSUE_LD(B1, idB1, cdB1);
    int i2 = (2 <= tl) ? 2 : tl;
    int i3 = (3 <= tl) ? 3 : tl;
    idA0 = ip0[i2]; cdA0 = cp0[i2]; idA1 = ip1[i2]; cdA1 = cp1[i2];
    idB0 = ip0[i3]; cdB0 = cp0[i3]; idB1 = ip1[i3]; cdB1 = cp1[i3];

    const int Teven = T & ~1;
    for (int t = 0; t < Teven; t += 2) {
        // even step (A sets), both chains
        f32x4 xr0 = pirA0 + pcrA0, xz0 = pizA0 + pczA0, xn0 = pinA0 + pcnA0;
        f32x4 xr1 = pirA1 + pcrA1, xz1 = pizA1 + pczA1, xn1 = pinA1 + pcnA1;
        ISSUE_LD(A0, idA0, cdA0);
        ISSUE_LD(A1, idA1, cdA1);
        { int tn = t + 4; if (tn > tl) tn = tl;
          idA0 = ip0[tn]; cdA0 = cp0[tn]; idA1 = ip1[tn]; cdA1 = cp1[tn]; }
        gru2(wrA, wzA, wnA, wrh, wzh, wnh, bhn4,
             xr0, xz0, xn0, xr1, xz1, xn1,
             h0, hsum0, hh0, hl0, h1, hsum1, hh1, hl1);

        // odd step (B sets), both chains
        xr0 = pirB0 + pcrB0; xz0 = pizB0 + pczB0; xn0 = pinB0 + pcnB0;
        xr1 = pirB1 + pcrB1; xz1 = pizB1 + pczB1; xn1 = pinB1 + pcnB1;
        ISSUE_LD(B0, idB0, cdB0);
        ISSUE_LD(B1, idB1, cdB1);
        { int tn = t + 5; if (tn > tl) tn = tl;
          idB0 = ip0[tn]; cdB0 = cp0[tn]; idB1 = ip1[tn]; cdB1 = cp1[tn]; }
        gru2(wrA, wzA, wnA, wrh, wzh, wnh, bhn4,
             xr0, xz0, xn0, xr1, xz1, xn1,
             h0, hsum0, hh0, hl0, h1, hsum1, hh1, hl1);
    }
    if (T & 1) {
        f32x4 xr0 = pirA0 + pcrA0, xz0 = pizA0 + pczA0, xn0 = pinA0 + pcnA0;
        f32x4 xr1 = pirA1 + pcrA1, xz1 = pizA1 + pczA1, xn1 = pinA1 + pcnA1;
        gru2(wrA, wzA, wnA, wrh, wzh, wnh, bhn4,
             xr0, xz0, xn0, xr1, xz1, xn1,
             h0, hsum0, hh0, hl0, h1, hsum1, hh1, hl1);
    }
#undef ISSUE_LD

    // ---- epilogue: both chains ----
    f32x4 avg0, t40, u40, avg1, t41, u41;
    epilogue_chain(b0, ti0, tc0, uid0, hi, hsum0, item_table, cat_table, user_table,
                   mha_Win, mha_bin, mha_Wout, mha_bout, avg0, t40, u40);
    epilogue_chain(b1, ti1, tc1, uid1, hi, hsum1, item_table, cat_table, user_table,
                   mha_Win, mha_bin, mha_Wout, mha_bout, avg1, t41, u41);

    if (act0) {
        float* er = all_enc + b0 * 48 + 4 * hi;
        *(f32x4*)er        = avg0;
        *(f32x4*)(er + 16) = t40;
        *(f32x4*)(er + 32) = u40;
    }
    if (act1) {
        float* er = all_enc + b1 * 48 + 4 * hi;
        *(f32x4*)er        = avg1;
        *(f32x4*)(er + 16) = t41;
        *(f32x4*)(er + 32) = u41;
    }

    const f32x4 zero4 = {0.f, 0.f, 0.f, 0.f};
    f32x4 a0 = act0 ? avg0 : zero4, t0v = act0 ? t40 : zero4, u0v = act0 ? u40 : zero4;
    f32x4 a1 = act1 ? avg1 : zero4, t1v = act1 ? t41 : zero4, u1v = act1 ? u41 : zero4;
    f32x4 sa = a0 + a1, st = t0v + t1v, su = u0v + u1v;
    f32x4 qa = a0 * a0 + a1 * a1, qt = t0v * t0v + t1v * t1v, qu = u0v * u0v + u1v * u1v;
#pragma unroll
    for (int m = 1; m <= 8; m <<= 1) {
#pragma unroll
        for (int q = 0; q < 4; ++q) {
            sa[q] += __shfl_xor(sa[q], m);
            st[q] += __shfl_xor(st[q], m);
            su[q] += __shfl_xor(su[q], m);
            qa[q] += __shfl_xor(qa[q], m);
            qt[q] += __shfl_xor(qt[q], m);
            qu[q] += __shfl_xor(qu[q], m);
        }
    }
    if (s == 0) {
        int c = 4 * hi;
#pragma unroll
        for (int q = 0; q < 4; ++q) {
            lds_part[wid][c + q]      = sa[q];
            lds_part[wid][16 + c + q] = st[q];
            lds_part[wid][32 + c + q] = su[q];
            lds_part[wid][48 + c + q] = qa[q];
            lds_part[wid][64 + c + q] = qt[q];
            lds_part[wid][80 + c + q] = qu[q];
        }
    }
    __syncthreads();
    if (tid < 96) {
        float v = lds_part[0][tid] + lds_part[1][tid] + lds_part[2][tid] + lds_part[3][tid];
        atomicAdd(&stats1[tid], v);
    }
}

// ---------------------------------------------------------------------------
// K3: fc1 with BN1-fold computed inline per block.
// ---------------------------------------------------------------------------
__global__ __launch_bounds__(256) void k_fc1(
    const float* __restrict__ all_enc, const float* __restrict__ stats,
    fp fc1_W, fp fc1_b, fp g1, fp b1,
    float* __restrict__ hbuf, float* __restrict__ stats2, int B)
{
    const int tid = threadIdx.x, lane = tid & 63, wid = tid >> 6;
    const int j = lane & 15, sl = lane >> 4;
    __shared__ float kk[48], mm[48];
    __shared__ float part[4][32];

    if (tid < 48) {
        float mu  = stats[tid] / (float)B;
        float var = stats[48 + tid] / (float)B - mu * mu;
        float k   = rsqrtf(var + BN_EPS);
        float gk  = g1[tid] * k;
        kk[tid] = gk;
        mm[tid] = b1[tid] - mu * gk;
    }
    __syncthreads();

    float w[48];
    float bj = fc1_b[j];
#pragma unroll
    for (int q = 0; q < 12; ++q) {
        float4 v = *(const float4*)&fc1_W[j * 48 + q * 4];
        w[q * 4 + 0] = v.x * kk[q * 4 + 0];
        w[q * 4 + 1] = v.y * kk[q * 4 + 1];
        w[q * 4 + 2] = v.z * kk[q * 4 + 2];
        w[q * 4 + 3] = v.w * kk[q * 4 + 3];
        bj += v.x * mm[q * 4 + 0] + v.y * mm[q * 4 + 1]
            + v.z * mm[q * 4 + 2] + v.w * mm[q * 4 + 3];
    }

    float sh = 0.f, sq = 0.f;
    for (long b = (long)blockIdx.x * 16 + wid * 4 + sl; b < B; b += (long)gridDim.x * 16) {
        const float* x = all_enc + b * 48;
        float acc = bj;
#pragma unroll
        for (int q = 0; q < 12; ++q) {
            float4 v = *(const float4*)&x[q * 4];
            acc += w[q * 4] * v.x + w[q * 4 + 1] * v.y + w[q * 4 + 2] * v.z + w[q * 4 + 3] * v.w;
        }
        float h = fmaxf(acc, 0.f);
        hbuf[b * 16 + j] = h;
        sh += h; sq += h * h;
    }
    sh += __shfl_xor(sh, 16); sh += __shfl_xor(sh, 32);
    sq += __shfl_xor(sq, 16); sq += __shfl_xor(sq, 32);
    if (sl == 0) { part[wid][j] = sh; part[wid][16 + j] = sq; }
    __syncthreads();
    if (tid < 32) {
        float v = part[0][tid] + part[1][tid] + part[2][tid] + part[3][tid];
        atomicAdd(&stats2[tid], v);
    }
}

// ---------------------------------------------------------------------------
// K4: logits + softmax, BN2-fold computed inline per block.
// ---------------------------------------------------------------------------
__global__ __launch_bounds__(256) void k_out(
    const float* __restrict__ hbuf, const float* __restrict__ stats2,
    fp fc2_W, fp fc2_b, fp g2, fp b2, float* __restrict__ out, int B)
{
    __shared__ float w[34];
    const int tid = threadIdx.x;
    if (tid < 32) {
        int c = tid & 15;
        float mu  = stats2[c] / (float)B;
        float var = stats2[16 + c] / (float)B - mu * mu;
        float gk  = g2[c] * rsqrtf(var + BN_EPS);
        w[tid] = fc2_W[tid] * gk;
    }
    if (tid < 2) {
        float acc = fc2_b[tid];
        for (int c = 0; c < 16; ++c) {
            float mu  = stats2[c] / (float)B;
            float var = stats2[16 + c] / (float)B - mu * mu;
            float gk  = g2[c] * rsqrtf(var + BN_EPS);
            acc += fc2_W[tid * 16 + c] * (b2[c] - mu * gk);
        }
        w[32 + tid] = acc;
    }
    __syncthreads();
    for (long b = (long)blockIdx.x * blockDim.x + threadIdx.x; b < B;
         b += (long)gridDim.x * blockDim.x) {
        const float* h = hbuf + b * 16;
        float l0 = w[32], l1 = w[33];
#pragma unroll
        for (int q = 0; q < 4; ++q) {
            float4 v = *(const float4*)&h[q * 4];
            l0 += w[q * 4] * v.x + w[q * 4 + 1] * v.y + w[q * 4 + 2] * v.z + w[q * 4 + 3] * v.w;
            l1 += w[16 + q * 4] * v.x + w[17 + q * 4] * v.y + w[18 + q * 4] * v.z + w[19 + q * 4] * v.w;
        }
        float m  = fmaxf(l0, l1);
        float e0 = __expf(l0 - m), e1 = __expf(l1 - m);
        float inv = frcp(e0 + e1);
        float2 p; p.x = e0 * inv; p.y = e1 * inv;
        *(float2*)&out[b * 2] = p;
    }
}

// ---------------------------------------------------------------------------
extern "C" void kernel_launch(void* const* d_in, const int* in_sizes, int n_in,
                              void* d_out, int out_size, void* d_ws, size_t ws_size,
                              hipStream_t stream)
{
    const int* user_id   = (const int*)d_in[0];
    const int* hist_item = (const int*)d_in[1];
    const int* hist_cat  = (const int*)d_in[2];
    const int* tgt_item  = (const int*)d_in[3];
    const int* tgt_cat   = (const int*)d_in[4];
    fp user_table = (fp)d_in[5];
    fp item_table = (fp)d_in[6];
    fp cat_table  = (fp)d_in[7];
    fp Wih = (fp)d_in[8],  Whh = (fp)d_in[9];
    fp bih = (fp)d_in[10], bhh = (fp)d_in[11];
    fp Win = (fp)d_in[12], binp = (fp)d_in[13];
    fp Wout = (fp)d_in[14], bout = (fp)d_in[15];
    fp g1 = (fp)d_in[16], b1 = (fp)d_in[17];
    fp fc1W = (fp)d_in[18], fc1b = (fp)d_in[19];
    fp g2 = (fp)d_in[20], b2 = (fp)d_in[21];
    fp fc2W = (fp)d_in[22], fc2b = (fp)d_in[23];

    const int B = in_sizes[0];
    const int T = in_sizes[1] / B;
    const int nItem = in_sizes[6] / 12;   // 10000
    const int nItemElems = nItem * 48;

    float* ws      = (float*)d_ws;
    float* P_item  = ws;                              // nItem*48
    float* P_cat   = P_item + (size_t)nItemElems;     // 520 (10 x 52 padded)
    float* stats   = P_cat + 520;                     // 128 (BN1 96 + BN2 32)
    float* stats2  = stats + 96;
    float* all_enc = stats + 128 + 8;                 // pad to 16B; B*48
    float* hbuf    = all_enc + (size_t)B * 48;        // B*16

    const int nItemBlocks = (nItemElems + 255) / 256;
    hipLaunchKernelGGL(k_precompute, dim3(nItemBlocks + 1), dim3(256), 0, stream,
                       Wih, bih, bhh, item_table, cat_table, P_item, P_cat, stats,
                       nItemElems, nItemBlocks);

    hipLaunchKernelGGL(k_gru, dim3((B + 127) / 128), dim3(256), 0, stream,
                       user_id, hist_item, hist_cat, tgt_item, tgt_cat,
                       user_table, item_table, cat_table, Whh, bhh,
                       Win, binp, Wout, bout, P_item, P_cat,
                       all_enc, stats, B, T);

    hipLaunchKernelGGL(k_fc1, dim3(512), dim3(256), 0, stream,
                       all_enc, stats, fc1W, fc1b, g1, b1, hbuf, stats2, B);

    hipLaunchKernelGGL(k_out, dim3((B + 255) / 256), dim3(256), 0, stream,
                       hbuf, stats2, fc2W, fc2b, g2, b2, (float*)d_out, B);
}

// Round 5
// 76.015 us; speedup vs baseline: 1.1823x; 1.1823x over previous
//
#include <hip/hip_runtime.h>

#define BN_EPS 1e-5f

typedef const float* fp;
typedef float f32x4 __attribute__((ext_vector_type(4)));
typedef _Float16 f16x2 __attribute__((ext_vector_type(2)));
typedef _Float16 f16x4 __attribute__((ext_vector_type(4)));
typedef _Float16 f16x8 __attribute__((ext_vector_type(8)));

// fast transcendentals: identical formulas to the previous (passing) kernel.
__device__ __forceinline__ float frcp(float x) { return __builtin_amdgcn_rcpf(x); }
__device__ __forceinline__ float sigm(float x) { return frcp(1.0f + __expf(-x)); }
__device__ __forceinline__ float tanh_fast(float x) { return 1.0f - 2.0f * frcp(1.0f + __expf(2.0f * x)); }

__device__ __forceinline__ f32x4 ld4(const float* p) { return *(const f32x4*)p; }
__device__ __forceinline__ float dot4(f32x4 a, f32x4 b) {
    return a[0] * b[0] + a[1] * b[1] + a[2] * b[2] + a[3] * b[3];
}

#define MFMA16(A, B, C) __builtin_amdgcn_mfma_f32_16x16x16f16((A), (B), (C), 0, 0, 0)
#define MFMA32(A, B, C) __builtin_amdgcn_mfma_f32_16x16x32_f16((A), (B), (C), 0, 0, 0)

// async global->LDS, 16B per lane; dest = uniform base + lane*16 (HW rule).
// No result VGPR => the compiler cannot sink it to the consumer; arrival is
// gated by our counted s_waitcnt vmcnt(N).
#define GLDS16(gp, lp) __builtin_amdgcn_global_load_lds( \
    (const __attribute__((address_space(1))) void*)(gp), \
    (__attribute__((address_space(3))) void*)(lp), 16, 0, 0)

// pack f32x4 -> f16x4 via v_cvt_pkrtz. RTZ fine: lo-residual absorbs rounding.
__device__ __forceinline__ f16x4 pk_f16(f32x4 v) {
    f16x2 lo = __builtin_bit_cast(f16x2, __builtin_amdgcn_cvt_pkrtz(v[0], v[1]));
    f16x2 hi = __builtin_bit_cast(f16x2, __builtin_amdgcn_cvt_pkrtz(v[2], v[3]));
    return __builtin_shufflevector(lo, hi, 0, 1, 2, 3);
}

// ---------------------------------------------------------------------------
// K1: fold item/cat embedding tables through Wih; zero the BN stats accums.
// P_cat rows padded to 52 floats and carry bih (+ bhh for the r,z gates).
// ---------------------------------------------------------------------------
__global__ __launch_bounds__(256) void k_precompute(
    fp Wih, fp bih, fp bhh, fp item_table, fp cat_table,
    float* __restrict__ P_item, float* __restrict__ P_cat,
    float* __restrict__ stats, int nItemElems, int nItemBlocks)
{
    __shared__ float w[768];
    for (int t = threadIdx.x; t < 768; t += blockDim.x) w[t] = Wih[t];
    __syncthreads();

    if ((int)blockIdx.x < nItemBlocks) {
        int idx = blockIdx.x * blockDim.x + threadIdx.x;
        if (idx < nItemElems) {
            int i = idx / 48, g = idx % 48;
            const float* row = item_table + (size_t)i * 12;
            float acc = 0.f;
#pragma unroll
            for (int k = 0; k < 12; ++k) acc += w[g * 16 + k] * row[k];
            P_item[idx] = acc;
        }
    } else {
        for (int t = threadIdx.x; t < 480; t += blockDim.x) {
            int c = t / 48, g = t % 48;
            float acc = bih[g] + (g < 32 ? bhh[g] : 0.f);
#pragma unroll
            for (int k = 0; k < 4; ++k) acc += w[g * 16 + 12 + k] * cat_table[c * 4 + k];
            P_cat[c * 52 + g] = acc;
        }
        if (threadIdx.x < 128) stats[threadIdx.x] = 0.f;   // stats1[96] + stats2[32]
    }
}

// ---------------------------------------------------------------------------
// K2: MFMA GRU, 16 samples/wave (2048 waves, 8/CU). Lane l: s=l&15, hi=l>>4.
// x-gate gather (P_item rows) is staged via global_load_lds into a per-wave
// double buffer, issued 2 steps ahead, consumed after a counted vmcnt(3)
// (never 0). History ids live in LDS (one-time coalesced-ish preload) so the
// loop's VMEM stream is EXACTLY 3 glds/step => vmcnt arithmetic is exact.
// D layout == next B layout: zero cross-lane traffic in the recurrence.
// ---------------------------------------------------------------------------
__global__ __launch_bounds__(256, 2) void k_gru(
    const int* __restrict__ user_id, const int* __restrict__ hist_item,
    const int* __restrict__ hist_cat, const int* __restrict__ tgt_item,
    const int* __restrict__ tgt_cat,
    fp user_table, fp item_table, fp cat_table,
    fp Whh, fp bhh,
    fp mha_Win, fp mha_bin, fp mha_Wout, fp mha_bout,
    const float* __restrict__ P_item, const float* __restrict__ P_cat,
    float* __restrict__ all_enc, float* __restrict__ stats1, int B, int T)
{
    __shared__ float s_pcat[520];               // 10 cats x 52 (padded)
    __shared__ float s_stage[4][2][3][256];     // [wave][parity][gate][lane*4]
    __shared__ int   s_iid[4][1040];            // [wave][s*65 + t]  (T <= 65)
    __shared__ int   s_cid[4][1040];
    __shared__ float lds_part[4][96];

    const int tid  = threadIdx.x;
    const int lane = tid & 63;
    const int wid  = tid >> 6;
    const int s    = lane & 15;
    const int hi   = lane >> 4;

    long b = (long)blockIdx.x * 64 + wid * 16 + s;
    const bool act = (b < B);
    if (!act) b = B - 1;            // clamp: loads stay valid, stores masked

    for (int t = tid; t < 520; t += 256) s_pcat[t] = P_cat[t];

    // epilogue indices (issued early; retired before the staged loop starts)
    const int ti  = tgt_item[b];
    const int tc  = tgt_cat[b];
    const int uid = user_id[b];

    // one-time id preload into LDS (each lane covers its sample, stride 4)
    {
        const int* ip = hist_item + b * T;
        const int* cp = hist_cat  + b * T;
        int* di = &s_iid[wid][s * 65];
        int* dc = &s_cid[wid][s * 65];
        for (int k = hi; k < T; k += 4) { di[k] = ip[k]; dc[k] = cp[k]; }
    }

    // Whh A-fragments (row = s, k = 4hi+i) per gate, split into f16 hi/lo
    f32x4 wrf = ld4(&Whh[(0  + s) * 16 + 4 * hi]);
    f32x4 wzf = ld4(&Whh[(16 + s) * 16 + 4 * hi]);
    f32x4 wnf = ld4(&Whh[(32 + s) * 16 + 4 * hi]);
    f16x4 wrh = __builtin_convertvector(wrf, f16x4);
    f16x4 wzh = __builtin_convertvector(wzf, f16x4);
    f16x4 wnh = __builtin_convertvector(wnf, f16x4);
    f16x4 wrl = __builtin_convertvector(wrf - __builtin_convertvector(wrh, f32x4), f16x4);
    f16x4 wzl = __builtin_convertvector(wzf - __builtin_convertvector(wzh, f32x4), f16x4);
    f16x4 wnl = __builtin_convertvector(wnf - __builtin_convertvector(wnh, f32x4), f16x4);
    f16x8 wrA = __builtin_shufflevector(wrh, wrl, 0, 1, 2, 3, 4, 5, 6, 7);
    f16x8 wzA = __builtin_shufflevector(wzh, wzl, 0, 1, 2, 3, 4, 5, 6, 7);
    f16x8 wnA = __builtin_shufflevector(wnh, wnl, 0, 1, 2, 3, 4, 5, 6, 7);
    const f32x4 bhn4 = ld4(&bhh[32 + 4 * hi]);

    f32x4 h    = {0.f, 0.f, 0.f, 0.f};
    f32x4 hsum = {0.f, 0.f, 0.f, 0.f};
    f16x4 hh = {}, hl = {};
    const f32x4 zero4 = {0.f, 0.f, 0.f, 0.f};

    __syncthreads();   // s_pcat + id tables ready; drains all prior VMEM

    const int T1 = T - 1;
    const int so = s * 65;
    float* stg = &s_stage[wid][0][0][0];   // parity stride 768, gate stride 256
    const int l4 = lane * 4;

    // prologue: stage steps 0 and 1 (exactly 6 glds outstanding)
    {
        int id0 = s_iid[wid][so];
        const char* g0 = (const char*)P_item + (size_t)(unsigned)id0 * 192u + hi * 16;
        GLDS16(g0,       stg);
        GLDS16(g0 + 64,  stg + 256);
        GLDS16(g0 + 128, stg + 512);
        int i1 = (T1 >= 1) ? 1 : 0;
        int id1 = s_iid[wid][so + i1];
        const char* g1 = (const char*)P_item + (size_t)(unsigned)id1 * 192u + hi * 16;
        GLDS16(g1,       stg + 768);
        GLDS16(g1 + 64,  stg + 768 + 256);
        GLDS16(g1 + 128, stg + 768 + 512);
    }
    int cd = s_cid[wid][so];

    for (int t = 0; t < T; ++t) {
        int t2 = (t + 2 > T1) ? T1 : t + 2;   // clamped: always 3 glds/step
        int t1 = (t + 1 > T1) ? T1 : t + 1;
        int idn = s_iid[wid][so + t2];
        int cdn = s_cid[wid][so + t1];

        // all but the newest 3 glds retired => step-t buffer is complete
        asm volatile("s_waitcnt vmcnt(3)" ::: "memory");

        float* bp = stg + (t & 1) * 768;
        f32x4 sr = ld4(bp + l4);
        f32x4 sz = ld4(bp + 256 + l4);
        f32x4 sn = ld4(bp + 512 + l4);
        const float* pcr = s_pcat + cd * 52 + 4 * hi;
        f32x4 pr = ld4(pcr), pz = ld4(pcr + 16), pn = ld4(pcr + 32);

        // secure LDS read data in VGPRs before re-targeting this buffer
        asm volatile("s_waitcnt lgkmcnt(0)" ::: "memory");

        const char* gn = (const char*)P_item + (size_t)(unsigned)idn * 192u + hi * 16;
        GLDS16(gn,       bp);
        GLDS16(gn + 64,  bp + 256);
        GLDS16(gn + 128, bp + 512);
        cd = cdn;

        f32x4 xr = sr + pr, xz = sz + pz, xn = sn + pn;
        f16x8 hB = __builtin_shufflevector(hh, hh, 0, 1, 2, 3, 0, 1, 2, 3);
        f32x4 aR = MFMA32(wrA, hB, xr);
        f32x4 aZ = MFMA32(wzA, hB, xz);
        f32x4 aN = MFMA32(wnA, hB, bhn4);
        f32x4 eR = MFMA16(wrh, hl, zero4);
        f32x4 eZ = MFMA16(wzh, hl, zero4);
        f32x4 eN = MFMA16(wnh, hl, zero4);
#pragma unroll
        for (int q = 0; q < 4; ++q) {
            float r = sigm(aR[q] + eR[q]);
            float z = sigm(aZ[q] + eZ[q]);
            float n = tanh_fast(fmaf(r, aN[q] + eN[q], xn[q]));
            h[q] = z * (h[q] - n) + n;
        }
        hsum += h;
        hh = pk_f16(h);
        f32x4 hb;
#pragma unroll
        for (int q = 0; q < 4; ++q) hb[q] = (float)hh[q];
        hl = pk_f16(h - hb);
    }

    // ---- epilogue: degenerate MHA -> A[b], all_enc row, BN1 stats ----
    const float* itr = item_table + (size_t)ti * 12;
    f32x4 tv0 = ld4(itr), tv1 = ld4(itr + 4), tv2 = ld4(itr + 8);
    f32x4 tv3 = ld4(cat_table + tc * 4);

    f32x4 vq;
#pragma unroll
    for (int q = 0; q < 4; ++q) {
        int row = 32 + 4 * hi + q;
        const float* wv = mha_Win + row * 16;
        vq[q] = mha_bin[row] + dot4(ld4(wv), tv0) + dot4(ld4(wv + 4), tv1)
              + dot4(ld4(wv + 8), tv2) + dot4(ld4(wv + 12), tv3);
    }
    f32x4 vg0, vg1, vg2, vg3;
#pragma unroll
    for (int q = 0; q < 4; ++q) {
        vg0[q] = __shfl_xor(vq[q], (hi ^ 0) << 4);
        vg1[q] = __shfl_xor(vq[q], (hi ^ 1) << 4);
        vg2[q] = __shfl_xor(vq[q], (hi ^ 2) << 4);
        vg3[q] = __shfl_xor(vq[q], (hi ^ 3) << 4);
    }
    f32x4 aj;
#pragma unroll
    for (int q = 0; q < 4; ++q) {
        int row = 4 * hi + q;
        const float* wo = mha_Wout + row * 16;
        aj[q] = mha_bout[row] + dot4(ld4(wo), vg0) + dot4(ld4(wo + 4), vg1)
              + dot4(ld4(wo + 8), vg2) + dot4(ld4(wo + 12), vg3);
    }
    f32x4 avg = aj * hsum;

    f32x4 u4 = ld4(user_table + (size_t)uid * 16 + 4 * hi);
    f32x4 t4 = (hi == 0) ? tv0 : (hi == 1) ? tv1 : (hi == 2) ? tv2 : tv3;

    if (act) {
        float* er = all_enc + b * 48 + 4 * hi;
        *(f32x4*)er        = avg;
        *(f32x4*)(er + 16) = t4;
        *(f32x4*)(er + 32) = u4;
    }

    f32x4 sa = avg, st = t4, su = u4;
    if (!act) { sa = zero4; st = zero4; su = zero4; }
    f32x4 qa = sa * sa, qt = st * st, qu = su * su;
#pragma unroll
    for (int m = 1; m <= 8; m <<= 1) {
#pragma unroll
        for (int q = 0; q < 4; ++q) {
            sa[q] += __shfl_xor(sa[q], m);
            st[q] += __shfl_xor(st[q], m);
            su[q] += __shfl_xor(su[q], m);
            qa[q] += __shfl_xor(qa[q], m);
            qt[q] += __shfl_xor(qt[q], m);
            qu[q] += __shfl_xor(qu[q], m);
        }
    }
    if (s == 0) {
        int c = 4 * hi;
#pragma unroll
        for (int q = 0; q < 4; ++q) {
            lds_part[wid][c + q]      = sa[q];
            lds_part[wid][16 + c + q] = st[q];
            lds_part[wid][32 + c + q] = su[q];
            lds_part[wid][48 + c + q] = qa[q];
            lds_part[wid][64 + c + q] = qt[q];
            lds_part[wid][80 + c + q] = qu[q];
        }
    }
    __syncthreads();
    if (tid < 96) {
        float v = lds_part[0][tid] + lds_part[1][tid] + lds_part[2][tid] + lds_part[3][tid];
        atomicAdd(&stats1[tid], v);
    }
}

// ---------------------------------------------------------------------------
// K3: fc1 with BN1-fold computed inline per block.
// ---------------------------------------------------------------------------
__global__ __launch_bounds__(256) void k_fc1(
    const float* __restrict__ all_enc, const float* __restrict__ stats,
    fp fc1_W, fp fc1_b, fp g1, fp b1,
    float* __restrict__ hbuf, float* __restrict__ stats2, int B)
{
    const int tid = threadIdx.x, lane = tid & 63, wid = tid >> 6;
    const int j = lane & 15, sl = lane >> 4;
    __shared__ float kk[48], mm[48];
    __shared__ float part[4][32];

    if (tid < 48) {
        float mu  = stats[tid] / (float)B;
        float var = stats[48 + tid] / (float)B - mu * mu;
        float k   = rsqrtf(var + BN_EPS);
        float gk  = g1[tid] * k;
        kk[tid] = gk;
        mm[tid] = b1[tid] - mu * gk;
    }
    __syncthreads();

    float w[48];
    float bj = fc1_b[j];
#pragma unroll
    for (int q = 0; q < 12; ++q) {
        float4 v = *(const float4*)&fc1_W[j * 48 + q * 4];
        w[q * 4 + 0] = v.x * kk[q * 4 + 0];
        w[q * 4 + 1] = v.y * kk[q * 4 + 1];
        w[q * 4 + 2] = v.z * kk[q * 4 + 2];
        w[q * 4 + 3] = v.w * kk[q * 4 + 3];
        bj += v.x * mm[q * 4 + 0] + v.y * mm[q * 4 + 1]
            + v.z * mm[q * 4 + 2] + v.w * mm[q * 4 + 3];
    }

    float sh = 0.f, sq = 0.f;
    for (long b = (long)blockIdx.x * 16 + wid * 4 + sl; b < B; b += (long)gridDim.x * 16) {
        const float* x = all_enc + b * 48;
        float acc = bj;
#pragma unroll
        for (int q = 0; q < 12; ++q) {
            float4 v = *(const float4*)&x[q * 4];
            acc += w[q * 4] * v.x + w[q * 4 + 1] * v.y + w[q * 4 + 2] * v.z + w[q * 4 + 3] * v.w;
        }
        float h = fmaxf(acc, 0.f);
        hbuf[b * 16 + j] = h;
        sh += h; sq += h * h;
    }
    sh += __shfl_xor(sh, 16); sh += __shfl_xor(sh, 32);
    sq += __shfl_xor(sq, 16); sq += __shfl_xor(sq, 32);
    if (sl == 0) { part[wid][j] = sh; part[wid][16 + j] = sq; }
    __syncthreads();
    if (tid < 32) {
        float v = part[0][tid] + part[1][tid] + part[2][tid] + part[3][tid];
        atomicAdd(&stats2[tid], v);
    }
}

// ---------------------------------------------------------------------------
// K4: logits + softmax, BN2-fold computed inline per block.
// ---------------------------------------------------------------------------
__global__ __launch_bounds__(256) void k_out(
    const float* __restrict__ hbuf, const float* __restrict__ stats2,
    fp fc2_W, fp fc2_b, fp g2, fp b2, float* __restrict__ out, int B)
{
    __shared__ float w[34];
    const int tid = threadIdx.x;
    if (tid < 32) {
        int c = tid & 15;
        float mu  = stats2[c] / (float)B;
        float var = stats2[16 + c] / (float)B - mu * mu;
        float gk  = g2[c] * rsqrtf(var + BN_EPS);
        w[tid] = fc2_W[tid] * gk;
    }
    if (tid < 2) {
        float acc = fc2_b[tid];
        for (int c = 0; c < 16; ++c) {
            float mu  = stats2[c] / (float)B;
            float var = stats2[16 + c] / (float)B - mu * mu;
            float gk  = g2[c] * rsqrtf(var + BN_EPS);
            acc += fc2_W[tid * 16 + c] * (b2[c] - mu * gk);
        }
        w[32 + tid] = acc;
    }
    __syncthreads();
    for (long b = (long)blockIdx.x * blockDim.x + threadIdx.x; b < B;
         b += (long)gridDim.x * blockDim.x) {
        const float* h = hbuf + b * 16;
        float l0 = w[32], l1 = w[33];
#pragma unroll
        for (int q = 0; q < 4; ++q) {
            float4 v = *(const float4*)&h[q * 4];
            l0 += w[q * 4] * v.x + w[q * 4 + 1] * v.y + w[q * 4 + 2] * v.z + w[q * 4 + 3] * v.w;
            l1 += w[16 + q * 4] * v.x + w[17 + q * 4] * v.y + w[18 + q * 4] * v.z + w[19 + q * 4] * v.w;
        }
        float m  = fmaxf(l0, l1);
        float e0 = __expf(l0 - m), e1 = __expf(l1 - m);
        float inv = frcp(e0 + e1);
        float2 p; p.x = e0 * inv; p.y = e1 * inv;
        *(float2*)&out[b * 2] = p;
    }
}

// ---------------------------------------------------------------------------
extern "C" void kernel_launch(void* const* d_in, const int* in_sizes, int n_in,
                              void* d_out, int out_size, void* d_ws, size_t ws_size,
                              hipStream_t stream)
{
    const int* user_id   = (const int*)d_in[0];
    const int* hist_item = (const int*)d_in[1];
    const int* hist_cat  = (const int*)d_in[2];
    const int* tgt_item  = (const int*)d_in[3];
    const int* tgt_cat   = (const int*)d_in[4];
    fp user_table = (fp)d_in[5];
    fp item_table = (fp)d_in[6];
    fp cat_table  = (fp)d_in[7];
    fp Wih = (fp)d_in[8],  Whh = (fp)d_in[9];
    fp bih = (fp)d_in[10], bhh = (fp)d_in[11];
    fp Win = (fp)d_in[12], binp = (fp)d_in[13];
    fp Wout = (fp)d_in[14], bout = (fp)d_in[15];
    fp g1 = (fp)d_in[16], b1 = (fp)d_in[17];
    fp fc1W = (fp)d_in[18], fc1b = (fp)d_in[19];
    fp g2 = (fp)d_in[20], b2 = (fp)d_in[21];
    fp fc2W = (fp)d_in[22], fc2b = (fp)d_in[23];

    const int B = in_sizes[0];
    const int T = in_sizes[1] / B;
    const int nItem = in_sizes[6] / 12;   // 10000
    const int nItemElems = nItem * 48;

    float* ws      = (float*)d_ws;
    float* P_item  = ws;                              // nItem*48
    float* P_cat   = P_item + (size_t)nItemElems;     // 520 (10 x 52 padded)
    float* stats   = P_cat + 520;                     // 128 (BN1 96 + BN2 32)
    float* stats2  = stats + 96;
    float* all_enc = stats + 128 + 8;                 // pad to 16B; B*48
    float* hbuf    = all_enc + (size_t)B * 48;        // B*16

    const int nItemBlocks = (nItemElems + 255) / 256;
    hipLaunchKernelGGL(k_precompute, dim3(nItemBlocks + 1), dim3(256), 0, stream,
                       Wih, bih, bhh, item_table, cat_table, P_item, P_cat, stats,
                       nItemElems, nItemBlocks);

    hipLaunchKernelGGL(k_gru, dim3((B + 63) / 64), dim3(256), 0, stream,
                       user_id, hist_item, hist_cat, tgt_item, tgt_cat,
                       user_table, item_table, cat_table, Whh, bhh,
                       Win, binp, Wout, bout, P_item, P_cat,
                       all_enc, stats, B, T);

    hipLaunchKernelGGL(k_fc1, dim3(512), dim3(256), 0, stream,
                       all_enc, stats, fc1W, fc1b, g1, b1, hbuf, stats2, B);

    hipLaunchKernelGGL(k_out, dim3((B + 255) / 256), dim3(256), 0, stream,
                       hbuf, stats2, fc2W, fc2b, g2, b2, (float*)d_out, B);
}

// Round 6
// 75.591 us; speedup vs baseline: 1.1889x; 1.0056x over previous
//
#include <hip/hip_runtime.h>

#define BN_EPS 1e-5f

typedef const float* fp;
typedef float f32x4 __attribute__((ext_vector_type(4)));
typedef _Float16 f16x2 __attribute__((ext_vector_type(2)));
typedef _Float16 f16x4 __attribute__((ext_vector_type(4)));
typedef _Float16 f16x8 __attribute__((ext_vector_type(8)));

// fast transcendentals: identical formulas to the previous (passing) kernel.
__device__ __forceinline__ float frcp(float x) { return __builtin_amdgcn_rcpf(x); }
__device__ __forceinline__ float sigm(float x) { return frcp(1.0f + __expf(-x)); }
__device__ __forceinline__ float tanh_fast(float x) { return 1.0f - 2.0f * frcp(1.0f + __expf(2.0f * x)); }

__device__ __forceinline__ f32x4 ld4(const float* p) { return *(const f32x4*)p; }
__device__ __forceinline__ float dot4(f32x4 a, f32x4 b) {
    return a[0] * b[0] + a[1] * b[1] + a[2] * b[2] + a[3] * b[3];
}

#define MFMA16(A, B, C) __builtin_amdgcn_mfma_f32_16x16x16f16((A), (B), (C), 0, 0, 0)
#define MFMA32(A, B, C) __builtin_amdgcn_mfma_f32_16x16x32_f16((A), (B), (C), 0, 0, 0)

// async global->LDS, 16B per lane; dest = uniform base + lane*16 (HW rule).
#define GLDS16(gp, lp) __builtin_amdgcn_global_load_lds( \
    (const __attribute__((address_space(1))) void*)(gp), \
    (__attribute__((address_space(3))) void*)(lp), 16, 0, 0)

// pack f32x4 -> f16x4 via v_cvt_pkrtz. RTZ fine: lo-residual absorbs rounding.
__device__ __forceinline__ f16x4 pk_f16(f32x4 v) {
    f16x2 lo = __builtin_bit_cast(f16x2, __builtin_amdgcn_cvt_pkrtz(v[0], v[1]));
    f16x2 hi = __builtin_bit_cast(f16x2, __builtin_amdgcn_cvt_pkrtz(v[2], v[3]));
    return __builtin_shufflevector(lo, hi, 0, 1, 2, 3);
}

// ---------------------------------------------------------------------------
// K1: pad item_table to itemP[10000][16] (cols 12..15 = 0); P_cat rows padded
// to 52 floats carrying Wih[:,12:16]@cat + bih (+ bhh for r,z); zero stats.
// ---------------------------------------------------------------------------
__global__ __launch_bounds__(256) void k_precompute(
    fp Wih, fp bih, fp bhh, fp item_table, fp cat_table,
    float* __restrict__ itemP, float* __restrict__ P_cat,
    float* __restrict__ stats, int nPadElems, int nPadBlocks)
{
    if ((int)blockIdx.x < nPadBlocks) {
        int idx = blockIdx.x * blockDim.x + threadIdx.x;
        if (idx < nPadElems) {
            int i = idx >> 4, j = idx & 15;
            itemP[idx] = (j < 12) ? item_table[i * 12 + j] : 0.f;
        }
    } else {
        for (int t = threadIdx.x; t < 480; t += blockDim.x) {
            int c = t / 48, g = t % 48;
            float acc = bih[g] + (g < 32 ? bhh[g] : 0.f);
#pragma unroll
            for (int k = 0; k < 4; ++k) acc += Wih[g * 16 + 12 + k] * cat_table[c * 4 + k];
            P_cat[c * 52 + g] = acc;
        }
        if (threadIdx.x < 128) stats[threadIdx.x] = 0.f;   // stats1[96] + stats2[32]
    }
}

// ---------------------------------------------------------------------------
// K2: MFMA GRU, 16 samples/wave. Lane l: s=l&15, hi=l>>4.
// K=32 MFMA computes Wih@e + Whh@h in ONE instruction per gate:
//   A=[Wih_gate | Whh_gate] (k 0..15 = e dims, 16..31 = h dims), B=[e|h].
// r,z gates: 3-term f16 split (A_hi*B_hi + A_lo*B_hi + A_hi*B_lo), C-chained.
// n gate: xn,hn kept separate (r multiplies only hn), each 2-MFMA split.
// Embedding rows (64B) staged via 1 glds/step into a 4-deep per-wave ring,
// consumed after counted vmcnt(3). D layout == next B layout: recurrence has
// zero cross-lane traffic.
// ---------------------------------------------------------------------------
__global__ __launch_bounds__(256, 2) void k_gru(
    const int* __restrict__ user_id, const int* __restrict__ hist_item,
    const int* __restrict__ hist_cat, const int* __restrict__ tgt_item,
    const int* __restrict__ tgt_cat,
    fp user_table, fp item_table, fp cat_table,
    fp Whh, fp bhh, fp Wih,
    fp mha_Win, fp mha_bin, fp mha_Wout, fp mha_bout,
    const float* __restrict__ itemP, const float* __restrict__ P_cat,
    float* __restrict__ all_enc, float* __restrict__ stats1, int B, int T)
{
    __shared__ float s_pcat[520];            // 10 cats x 52 (padded)
    __shared__ float s_stage[4][4][256];     // [wave][depth][lane*4] 16KB
    __shared__ int   s_iid[4][1040];         // [wave][s*65 + t]  (T <= 65)
    __shared__ int   s_cid[4][1040];
    __shared__ float lds_part[4][96];

    const int tid  = threadIdx.x;
    const int lane = tid & 63;
    const int wid  = tid >> 6;
    const int s    = lane & 15;
    const int hi   = lane >> 4;

    long b = (long)blockIdx.x * 64 + wid * 16 + s;
    const bool act = (b < B);
    if (!act) b = B - 1;

    for (int t = tid; t < 520; t += 256) s_pcat[t] = P_cat[t];

    // epilogue indices (retire before the staged loop starts)
    const int ti  = tgt_item[b];
    const int tc  = tgt_cat[b];
    const int uid = user_id[b];

    // one-time id preload into LDS
    {
        const int* ip = hist_item + b * T;
        const int* cp = hist_cat  + b * T;
        int* di = &s_iid[wid][s * 65];
        int* dc = &s_cid[wid][s * 65];
        for (int k = hi; k < T; k += 4) { di[k] = ip[k]; dc[k] = cp[k]; }
    }

    // ---- weight fragments (one-time) ----
    // Whh / Wih gate rows (A row m = s, k = 4hi+i), f16 hi/lo split
    f32x4 whrf = ld4(&Whh[(0  + s) * 16 + 4 * hi]);
    f32x4 whzf = ld4(&Whh[(16 + s) * 16 + 4 * hi]);
    f32x4 whnf = ld4(&Whh[(32 + s) * 16 + 4 * hi]);
    f32x4 wirf = ld4(&Wih[(0  + s) * 16 + 4 * hi]);
    f32x4 wizf = ld4(&Wih[(16 + s) * 16 + 4 * hi]);
    f32x4 winf = ld4(&Wih[(32 + s) * 16 + 4 * hi]);
    f16x4 whr_h = __builtin_convertvector(whrf, f16x4);
    f16x4 whz_h = __builtin_convertvector(whzf, f16x4);
    f16x4 whn_h = __builtin_convertvector(whnf, f16x4);
    f16x4 wir_h = __builtin_convertvector(wirf, f16x4);
    f16x4 wiz_h = __builtin_convertvector(wizf, f16x4);
    f16x4 win_h = __builtin_convertvector(winf, f16x4);
    f16x4 whr_l = __builtin_convertvector(whrf - __builtin_convertvector(whr_h, f32x4), f16x4);
    f16x4 whz_l = __builtin_convertvector(whzf - __builtin_convertvector(whz_h, f32x4), f16x4);
    f16x4 whn_l = __builtin_convertvector(whnf - __builtin_convertvector(whn_h, f32x4), f16x4);
    f16x4 wir_l = __builtin_convertvector(wirf - __builtin_convertvector(wir_h, f32x4), f16x4);
    f16x4 wiz_l = __builtin_convertvector(wizf - __builtin_convertvector(wiz_h, f32x4), f16x4);
    f16x4 win_l = __builtin_convertvector(winf - __builtin_convertvector(win_h, f32x4), f16x4);
    // merged A frags: [Wih | Whh] per gate (hi and lo), and n-gate split frags
    f16x8 Ar  = __builtin_shufflevector(wir_h, whr_h, 0, 1, 2, 3, 4, 5, 6, 7);
    f16x8 ArL = __builtin_shufflevector(wir_l, whr_l, 0, 1, 2, 3, 4, 5, 6, 7);
    f16x8 Az  = __builtin_shufflevector(wiz_h, whz_h, 0, 1, 2, 3, 4, 5, 6, 7);
    f16x8 AzL = __builtin_shufflevector(wiz_l, whz_l, 0, 1, 2, 3, 4, 5, 6, 7);
    f16x8 Anx = __builtin_shufflevector(win_h, win_l, 0, 1, 2, 3, 4, 5, 6, 7);  // [hi|lo] on e
    f16x8 Anh = __builtin_shufflevector(whn_h, whn_l, 0, 1, 2, 3, 4, 5, 6, 7);  // [hi|lo] on h
    const f32x4 bhn4 = ld4(&bhh[32 + 4 * hi]);

    f32x4 h    = {0.f, 0.f, 0.f, 0.f};
    f32x4 hsum = {0.f, 0.f, 0.f, 0.f};
    f16x4 hh = {}, hl = {};

    __syncthreads();   // s_pcat + id tables ready; drains all prior VMEM

    const int T1 = T - 1;
    const int so = s * 65;
    float* stg = &s_stage[wid][0][0];       // buffer d at stg + d*256 floats
    const int l4 = lane * 4;

    // prologue: stage steps 0..3 (4 glds outstanding)
#pragma unroll
    for (int d = 0; d < 4; ++d) {
        int td = (d > T1) ? T1 : d;
        int idd = s_iid[wid][so + td];
        GLDS16((const char*)itemP + (size_t)(unsigned)idd * 64u + hi * 16, stg + d * 256);
    }
    int cd = s_cid[wid][so];

    for (int t = 0; t < T; ++t) {
        int t4 = (t + 4 > T1) ? T1 : t + 4;
        int t1 = (t + 1 > T1) ? T1 : t + 1;
        int idn = s_iid[wid][so + t4];
        int cdn = s_cid[wid][so + t1];

        // all but the newest 3 glds retired => step-t buffer complete
        asm volatile("s_waitcnt vmcnt(3)" ::: "memory");

        float* bp = stg + (t & 3) * 256;
        f32x4 e4 = ld4(bp + l4);
        const float* pc = s_pcat + cd * 52 + 4 * hi;
        f32x4 pcr = ld4(pc), pcz = ld4(pc + 16), pcn = ld4(pc + 32);

        // secure LDS reads in VGPRs before re-targeting this buffer
        asm volatile("s_waitcnt lgkmcnt(0)" ::: "memory");

        GLDS16((const char*)itemP + (size_t)(unsigned)idn * 64u + hi * 16, bp);
        cd = cdn;

        // e -> f16 hi/lo split
        f16x4 e_h = pk_f16(e4);
        f32x4 eb;
#pragma unroll
        for (int q = 0; q < 4; ++q) eb[q] = (float)e_h[q];
        f16x4 e_l = pk_f16(e4 - eb);

        f16x8 Bhh = __builtin_shufflevector(e_h, hh, 0, 1, 2, 3, 4, 5, 6, 7);  // [e|h] hi
        f16x8 Bll = __builtin_shufflevector(e_l, hl, 0, 1, 2, 3, 4, 5, 6, 7);  // [e|h] lo
        f16x8 Bee = __builtin_shufflevector(e_h, e_h, 0, 1, 2, 3, 0, 1, 2, 3);
        f16x8 Bh2 = __builtin_shufflevector(hh, hh, 0, 1, 2, 3, 0, 1, 2, 3);

        // r,z: 3-term chain (lo*hi first: needs only hi B-frags)
        f32x4 aR = MFMA32(Ar, Bhh, MFMA32(Ar, Bll, MFMA32(ArL, Bhh, pcr)));
        f32x4 aZ = MFMA32(Az, Bhh, MFMA32(Az, Bll, MFMA32(AzL, Bhh, pcz)));
        // n: xn (e path) and hn (h path) separate
        f32x4 xn = MFMA16(win_h, e_l, MFMA32(Anx, Bee, pcn));
        f32x4 hn = MFMA16(whn_h, hl, MFMA32(Anh, Bh2, bhn4));

#pragma unroll
        for (int q = 0; q < 4; ++q) {
            float r = sigm(aR[q]);
            float z = sigm(aZ[q]);
            float n = tanh_fast(fmaf(r, hn[q], xn[q]));
            h[q] = z * (h[q] - n) + n;
        }
        hsum += h;
        hh = pk_f16(h);
        f32x4 hb;
#pragma unroll
        for (int q = 0; q < 4; ++q) hb[q] = (float)hh[q];
        hl = pk_f16(h - hb);
    }

    // ---- epilogue: degenerate MHA -> A[b], all_enc row, BN1 stats ----
    const float* itr = item_table + (size_t)ti * 12;
    f32x4 tv0 = ld4(itr), tv1 = ld4(itr + 4), tv2 = ld4(itr + 8);
    f32x4 tv3 = ld4(cat_table + tc * 4);

    f32x4 vq;
#pragma unroll
    for (int q = 0; q < 4; ++q) {
        int row = 32 + 4 * hi + q;
        const float* wv = mha_Win + row * 16;
        vq[q] = mha_bin[row] + dot4(ld4(wv), tv0) + dot4(ld4(wv + 4), tv1)
              + dot4(ld4(wv + 8), tv2) + dot4(ld4(wv + 12), tv3);
    }
    f32x4 vg0, vg1, vg2, vg3;
#pragma unroll
    for (int q = 0; q < 4; ++q) {
        vg0[q] = __shfl_xor(vq[q], (hi ^ 0) << 4);
        vg1[q] = __shfl_xor(vq[q], (hi ^ 1) << 4);
        vg2[q] = __shfl_xor(vq[q], (hi ^ 2) << 4);
        vg3[q] = __shfl_xor(vq[q], (hi ^ 3) << 4);
    }
    f32x4 aj;
#pragma unroll
    for (int q = 0; q < 4; ++q) {
        int row = 4 * hi + q;
        const float* wo = mha_Wout + row * 16;
        aj[q] = mha_bout[row] + dot4(ld4(wo), vg0) + dot4(ld4(wo + 4), vg1)
              + dot4(ld4(wo + 8), vg2) + dot4(ld4(wo + 12), vg3);
    }
    f32x4 avg = aj * hsum;

    f32x4 u4 = ld4(user_table + (size_t)uid * 16 + 4 * hi);
    f32x4 t4v = (hi == 0) ? tv0 : (hi == 1) ? tv1 : (hi == 2) ? tv2 : tv3;

    if (act) {
        float* er = all_enc + b * 48 + 4 * hi;
        *(f32x4*)er        = avg;
        *(f32x4*)(er + 16) = t4v;
        *(f32x4*)(er + 32) = u4;
    }

    const f32x4 zero4 = {0.f, 0.f, 0.f, 0.f};
    f32x4 sa = act ? avg : zero4, st = act ? t4v : zero4, su = act ? u4 : zero4;
    f32x4 qa = sa * sa, qt = st * st, qu = su * su;
#pragma unroll
    for (int m = 1; m <= 8; m <<= 1) {
#pragma unroll
        for (int q = 0; q < 4; ++q) {
            sa[q] += __shfl_xor(sa[q], m);
            st[q] += __shfl_xor(st[q], m);
            su[q] += __shfl_xor(su[q], m);
            qa[q] += __shfl_xor(qa[q], m);
            qt[q] += __shfl_xor(qt[q], m);
            qu[q] += __shfl_xor(qu[q], m);
        }
    }
    if (s == 0) {
        int c = 4 * hi;
#pragma unroll
        for (int q = 0; q < 4; ++q) {
            lds_part[wid][c + q]      = sa[q];
            lds_part[wid][16 + c + q] = st[q];
            lds_part[wid][32 + c + q] = su[q];
            lds_part[wid][48 + c + q] = qa[q];
            lds_part[wid][64 + c + q] = qt[q];
            lds_part[wid][80 + c + q] = qu[q];
        }
    }
    __syncthreads();
    if (tid < 96) {
        float v = lds_part[0][tid] + lds_part[1][tid] + lds_part[2][tid] + lds_part[3][tid];
        atomicAdd(&stats1[tid], v);
    }
}

// ---------------------------------------------------------------------------
// K3: fc1 with BN1-fold computed inline per block.
// ---------------------------------------------------------------------------
__global__ __launch_bounds__(256) void k_fc1(
    const float* __restrict__ all_enc, const float* __restrict__ stats,
    fp fc1_W, fp fc1_b, fp g1, fp b1,
    float* __restrict__ hbuf, float* __restrict__ stats2, int B)
{
    const int tid = threadIdx.x, lane = tid & 63, wid = tid >> 6;
    const int j = lane & 15, sl = lane >> 4;
    __shared__ float kk[48], mm[48];
    __shared__ float part[4][32];

    if (tid < 48) {
        float mu  = stats[tid] / (float)B;
        float var = stats[48 + tid] / (float)B - mu * mu;
        float k   = rsqrtf(var + BN_EPS);
        float gk  = g1[tid] * k;
        kk[tid] = gk;
        mm[tid] = b1[tid] - mu * gk;
    }
    __syncthreads();

    float w[48];
    float bj = fc1_b[j];
#pragma unroll
    for (int q = 0; q < 12; ++q) {
        float4 v = *(const float4*)&fc1_W[j * 48 + q * 4];
        w[q * 4 + 0] = v.x * kk[q * 4 + 0];
        w[q * 4 + 1] = v.y * kk[q * 4 + 1];
        w[q * 4 + 2] = v.z * kk[q * 4 + 2];
        w[q * 4 + 3] = v.w * kk[q * 4 + 3];
        bj += v.x * mm[q * 4 + 0] + v.y * mm[q * 4 + 1]
            + v.z * mm[q * 4 + 2] + v.w * mm[q * 4 + 3];
    }

    float sh = 0.f, sq = 0.f;
    for (long b = (long)blockIdx.x * 16 + wid * 4 + sl; b < B; b += (long)gridDim.x * 16) {
        const float* x = all_enc + b * 48;
        float acc = bj;
#pragma unroll
        for (int q = 0; q < 12; ++q) {
            float4 v = *(const float4*)&x[q * 4];
            acc += w[q * 4] * v.x + w[q * 4 + 1] * v.y + w[q * 4 + 2] * v.z + w[q * 4 + 3] * v.w;
        }
        float h = fmaxf(acc, 0.f);
        hbuf[b * 16 + j] = h;
        sh += h; sq += h * h;
    }
    sh += __shfl_xor(sh, 16); sh += __shfl_xor(sh, 32);
    sq += __shfl_xor(sq, 16); sq += __shfl_xor(sq, 32);
    if (sl == 0) { part[wid][j] = sh; part[wid][16 + j] = sq; }
    __syncthreads();
    if (tid < 32) {
        float v = part[0][tid] + part[1][tid] + part[2][tid] + part[3][tid];
        atomicAdd(&stats2[tid], v);
    }
}

// ---------------------------------------------------------------------------
// K4: logits + softmax, BN2-fold computed inline per block.
// ---------------------------------------------------------------------------
__global__ __launch_bounds__(256) void k_out(
    const float* __restrict__ hbuf, const float* __restrict__ stats2,
    fp fc2_W, fp fc2_b, fp g2, fp b2, float* __restrict__ out, int B)
{
    __shared__ float w[34];
    const int tid = threadIdx.x;
    if (tid < 32) {
        int c = tid & 15;
        float mu  = stats2[c] / (float)B;
        float var = stats2[16 + c] / (float)B - mu * mu;
        float gk  = g2[c] * rsqrtf(var + BN_EPS);
        w[tid] = fc2_W[tid] * gk;
    }
    if (tid < 2) {
        float acc = fc2_b[tid];
        for (int c = 0; c < 16; ++c) {
            float mu  = stats2[c] / (float)B;
            float var = stats2[16 + c] / (float)B - mu * mu;
            float gk  = g2[c] * rsqrtf(var + BN_EPS);
            acc += fc2_W[tid * 16 + c] * (b2[c] - mu * gk);
        }
        w[32 + tid] = acc;
    }
    __syncthreads();
    for (long b = (long)blockIdx.x * blockDim.x + threadIdx.x; b < B;
         b += (long)gridDim.x * blockDim.x) {
        const float* h = hbuf + b * 16;
        float l0 = w[32], l1 = w[33];
#pragma unroll
        for (int q = 0; q < 4; ++q) {
            float4 v = *(const float4*)&h[q * 4];
            l0 += w[q * 4] * v.x + w[q * 4 + 1] * v.y + w[q * 4 + 2] * v.z + w[q * 4 + 3] * v.w;
            l1 += w[16 + q * 4] * v.x + w[17 + q * 4] * v.y + w[18 + q * 4] * v.z + w[19 + q * 4] * v.w;
        }
        float m  = fmaxf(l0, l1);
        float e0 = __expf(l0 - m), e1 = __expf(l1 - m);
        float inv = frcp(e0 + e1);
        float2 p; p.x = e0 * inv; p.y = e1 * inv;
        *(float2*)&out[b * 2] = p;
    }
}

// ---------------------------------------------------------------------------
extern "C" void kernel_launch(void* const* d_in, const int* in_sizes, int n_in,
                              void* d_out, int out_size, void* d_ws, size_t ws_size,
                              hipStream_t stream)
{
    const int* user_id   = (const int*)d_in[0];
    const int* hist_item = (const int*)d_in[1];
    const int* hist_cat  = (const int*)d_in[2];
    const int* tgt_item  = (const int*)d_in[3];
    const int* tgt_cat   = (const int*)d_in[4];
    fp user_table = (fp)d_in[5];
    fp item_table = (fp)d_in[6];
    fp cat_table  = (fp)d_in[7];
    fp Wih = (fp)d_in[8],  Whh = (fp)d_in[9];
    fp bih = (fp)d_in[10], bhh = (fp)d_in[11];
    fp Win = (fp)d_in[12], binp = (fp)d_in[13];
    fp Wout = (fp)d_in[14], bout = (fp)d_in[15];
    fp g1 = (fp)d_in[16], b1 = (fp)d_in[17];
    fp fc1W = (fp)d_in[18], fc1b = (fp)d_in[19];
    fp g2 = (fp)d_in[20], b2 = (fp)d_in[21];
    fp fc2W = (fp)d_in[22], fc2b = (fp)d_in[23];

    const int B = in_sizes[0];
    const int T = in_sizes[1] / B;
    const int nItem = in_sizes[6] / 12;   // 10000
    const int nPadElems = nItem * 16;

    float* ws      = (float*)d_ws;
    float* itemP   = ws;                              // nItem*16 (padded rows)
    float* P_cat   = itemP + (size_t)nPadElems;       // 520 (10 x 52 padded)
    float* stats   = P_cat + 520;                     // 128 (BN1 96 + BN2 32)
    float* stats2  = stats + 96;
    float* all_enc = stats + 128 + 8;                 // pad to 16B; B*48
    float* hbuf    = all_enc + (size_t)B * 48;        // B*16

    const int nPadBlocks = (nPadElems + 255) / 256;
    hipLaunchKernelGGL(k_precompute, dim3(nPadBlocks + 1), dim3(256), 0, stream,
                       Wih, bih, bhh, item_table, cat_table, itemP, P_cat, stats,
                       nPadElems, nPadBlocks);

    hipLaunchKernelGGL(k_gru, dim3((B + 63) / 64), dim3(256), 0, stream,
                       user_id, hist_item, hist_cat, tgt_item, tgt_cat,
                       user_table, item_table, cat_table, Whh, bhh, Wih,
                       Win, binp, Wout, bout, itemP, P_cat,
                       all_enc, stats, B, T);

    hipLaunchKernelGGL(k_fc1, dim3(512), dim3(256), 0, stream,
                       all_enc, stats, fc1W, fc1b, g1, b1, hbuf, stats2, B);

    hipLaunchKernelGGL(k_out, dim3((B + 255) / 256), dim3(256), 0, stream,
                       hbuf, stats2, fc2W, fc2b, g2, b2, (float*)d_out, B);
}

// Round 7
// 74.851 us; speedup vs baseline: 1.2007x; 1.0099x over previous
//
#include <hip/hip_runtime.h>

#define BN_EPS 1e-5f

typedef const float* fp;
typedef float f32x4 __attribute__((ext_vector_type(4)));
typedef _Float16 f16x2 __attribute__((ext_vector_type(2)));
typedef _Float16 f16x4 __attribute__((ext_vector_type(4)));
typedef _Float16 f16x8 __attribute__((ext_vector_type(8)));

// fast transcendentals: identical formulas to the previous (passing) kernel.
__device__ __forceinline__ float frcp(float x) { return __builtin_amdgcn_rcpf(x); }
__device__ __forceinline__ float sigm(float x) { return frcp(1.0f + __expf(-x)); }
__device__ __forceinline__ float tanh_fast(float x) { return 1.0f - 2.0f * frcp(1.0f + __expf(2.0f * x)); }

__device__ __forceinline__ f32x4 ld4(const float* p) { return *(const f32x4*)p; }
__device__ __forceinline__ float dot4(f32x4 a, f32x4 b) {
    return a[0] * b[0] + a[1] * b[1] + a[2] * b[2] + a[3] * b[3];
}

#define MFMA16(A, B, C) __builtin_amdgcn_mfma_f32_16x16x16f16((A), (B), (C), 0, 0, 0)
#define MFMA32(A, B, C) __builtin_amdgcn_mfma_f32_16x16x32_f16((A), (B), (C), 0, 0, 0)

// async global->LDS, 16B per lane; dest = uniform base + lane*16 (HW rule).
#define GLDS16(gp, lp) __builtin_amdgcn_global_load_lds( \
    (const __attribute__((address_space(1))) void*)(gp), \
    (__attribute__((address_space(3))) void*)(lp), 16, 0, 0)

// pack f32x4 -> f16x4 via v_cvt_pkrtz. RTZ fine: lo-residual absorbs rounding.
__device__ __forceinline__ f16x4 pk_f16(f32x4 v) {
    f16x2 lo = __builtin_bit_cast(f16x2, __builtin_amdgcn_cvt_pkrtz(v[0], v[1]));
    f16x2 hi = __builtin_bit_cast(f16x2, __builtin_amdgcn_cvt_pkrtz(v[2], v[3]));
    return __builtin_shufflevector(lo, hi, 0, 1, 2, 3);
}

// ---------------------------------------------------------------------------
// K0: zero the BN stats accumulators (all other precompute eliminated — the
// gather now reads the raw item/cat tables and biases live in registers).
// ---------------------------------------------------------------------------
__global__ void k_zero(float* __restrict__ stats) { stats[threadIdx.x] = 0.f; }

// ---------------------------------------------------------------------------
// K2: MFMA GRU, 16 samples/wave. Lane l: s=l&15, hi=l>>4.
// B-fragment k=0..15 = [item_emb(12) | cat_emb(4)]: the hi==3 lanes' gather
// source is cat_table, so Wih[:,12:16]@cat happens inside the K=32 MFMA and
// the gate C-operands are CONSTANT bias registers (bih+bhh) — no per-step
// LDS table reads. Per step: vmcnt(2) (slot t+1 landed) -> ds_read slot t+1
// into regs for NEXT step (lgkm wait hidden under compute) -> compute on
// eCur -> lgkmcnt(0) (free) -> glds for t+4. Exactly one glds between
// "memory" fences => vmcnt counting is scheduler-proof; tail ids clamped so
// the count stays uniform. D layout == next B layout: zero cross-lane
// traffic in the recurrence.
// ---------------------------------------------------------------------------
__device__ __forceinline__ void gru_step_mf(
    f32x4 e4,
    const f16x8& Ar, const f16x8& ArL, const f16x8& Az, const f16x8& AzL,
    const f16x8& Anx, const f16x8& Anh, const f16x4& winh, const f16x4& whnh,
    const f32x4& br4, const f32x4& bz4, const f32x4& bxn4, const f32x4& bhn4,
    f32x4& h, f32x4& hsum, f16x4& hh, f16x4& hl)
{
    const f32x4 z4 = {0.f, 0.f, 0.f, 0.f};
    f16x4 e_h = pk_f16(e4);
    f32x4 eb;
#pragma unroll
    for (int q = 0; q < 4; ++q) eb[q] = (float)e_h[q];
    f16x4 e_l = pk_f16(e4 - eb);
    f16x8 Bhh = __builtin_shufflevector(e_h, hh, 0, 1, 2, 3, 4, 5, 6, 7);
    f16x8 Bll = __builtin_shufflevector(e_l, hl, 0, 1, 2, 3, 4, 5, 6, 7);
    f16x8 Bee = __builtin_shufflevector(e_h, e_h, 0, 1, 2, 3, 0, 1, 2, 3);
    f16x8 Bh2 = __builtin_shufflevector(hh, hh, 0, 1, 2, 3, 0, 1, 2, 3);
    // independent MFMAs (critical path = 1 MFMA + adds, not a 3-chain)
    f32x4 r0 = MFMA32(Ar,  Bhh, br4);
    f32x4 r1 = MFMA32(ArL, Bhh, z4);
    f32x4 r2 = MFMA32(Ar,  Bll, z4);
    f32x4 zg0 = MFMA32(Az,  Bhh, bz4);
    f32x4 zg1 = MFMA32(AzL, Bhh, z4);
    f32x4 zg2 = MFMA32(Az,  Bll, z4);
    f32x4 x0 = MFMA32(Anx, Bee, bxn4);
    f32x4 x1 = MFMA16(winh, e_l, z4);
    f32x4 n0 = MFMA32(Anh, Bh2, bhn4);
    f32x4 n1 = MFMA16(whnh, hl, z4);
    f32x4 aR = (r0 + r1) + r2;
    f32x4 aZ = (zg0 + zg1) + zg2;
    f32x4 xn = x0 + x1;
    f32x4 hn = n0 + n1;
#pragma unroll
    for (int q = 0; q < 4; ++q) {
        float r = sigm(aR[q]);
        float z = sigm(aZ[q]);
        float n = tanh_fast(fmaf(r, hn[q], xn[q]));
        h[q] = z * (h[q] - n) + n;
    }
    hsum += h;
    hh = pk_f16(h);
    f32x4 hb;
#pragma unroll
    for (int q = 0; q < 4; ++q) hb[q] = (float)hh[q];
    hl = pk_f16(h - hb);
}

__global__ __launch_bounds__(256, 2) void k_gru(
    const int* __restrict__ user_id, const int* __restrict__ hist_item,
    const int* __restrict__ hist_cat, const int* __restrict__ tgt_item,
    const int* __restrict__ tgt_cat,
    fp user_table, fp item_table, fp cat_table,
    fp Whh, fp bhh, fp Wih, fp bih,
    fp mha_Win, fp mha_bin, fp mha_Wout, fp mha_bout,
    float* __restrict__ all_enc, float* __restrict__ stats1, int B, int T)
{
    __shared__ float    s_stage[4][4][256];   // 16KB [wave][slot][lane*4]
    __shared__ unsigned s_ids[4][16 * 67];    // packed (cd<<16)|id, stride 67
    __shared__ float    lds_part[4][96];

    const int tid  = threadIdx.x;
    const int lane = tid & 63;
    const int wid  = tid >> 6;
    const int s    = lane & 15;
    const int hi   = lane >> 4;

    long b = (long)blockIdx.x * 64 + wid * 16 + s;
    const bool act = (b < B);
    if (!act) b = B - 1;

    // epilogue indices: force-materialize BEFORE the barrier so their VMEM
    // retires outside the counted loop region.
    const int ti  = tgt_item[b];
    const int tc  = tgt_cat[b];
    const int uid = user_id[b];
    asm volatile("" :: "v"(ti), "v"(tc), "v"(uid));

    // one-time packed id preload into LDS
    {
        const int* ip = hist_item + b * T;
        const int* cp = hist_cat  + b * T;
        unsigned* d = &s_ids[wid][s * 67];
        for (int k = hi; k < T; k += 4)
            d[k] = (unsigned)ip[k] | ((unsigned)cp[k] << 16);
    }

    // ---- weight fragments + constant gate biases (one-time) ----
    f32x4 wirf = ld4(&Wih[(0  + s) * 16 + 4 * hi]);
    f32x4 wizf = ld4(&Wih[(16 + s) * 16 + 4 * hi]);
    f32x4 winf = ld4(&Wih[(32 + s) * 16 + 4 * hi]);
    f32x4 whrf = ld4(&Whh[(0  + s) * 16 + 4 * hi]);
    f32x4 whzf = ld4(&Whh[(16 + s) * 16 + 4 * hi]);
    f32x4 whnf = ld4(&Whh[(32 + s) * 16 + 4 * hi]);
    f16x4 wir_h = __builtin_convertvector(wirf, f16x4);
    f16x4 wiz_h = __builtin_convertvector(wizf, f16x4);
    f16x4 win_h = __builtin_convertvector(winf, f16x4);
    f16x4 whr_h = __builtin_convertvector(whrf, f16x4);
    f16x4 whz_h = __builtin_convertvector(whzf, f16x4);
    f16x4 whn_h = __builtin_convertvector(whnf, f16x4);
    f16x4 wir_l = __builtin_convertvector(wirf - __builtin_convertvector(wir_h, f32x4), f16x4);
    f16x4 wiz_l = __builtin_convertvector(wizf - __builtin_convertvector(wiz_h, f32x4), f16x4);
    f16x4 win_l = __builtin_convertvector(winf - __builtin_convertvector(win_h, f32x4), f16x4);
    f16x4 whr_l = __builtin_convertvector(whrf - __builtin_convertvector(whr_h, f32x4), f16x4);
    f16x4 whz_l = __builtin_convertvector(whzf - __builtin_convertvector(whz_h, f32x4), f16x4);
    f16x4 whn_l = __builtin_convertvector(whnf - __builtin_convertvector(whn_h, f32x4), f16x4);
    f16x8 Ar  = __builtin_shufflevector(wir_h, whr_h, 0, 1, 2, 3, 4, 5, 6, 7);
    f16x8 ArL = __builtin_shufflevector(wir_l, whr_l, 0, 1, 2, 3, 4, 5, 6, 7);
    f16x8 Az  = __builtin_shufflevector(wiz_h, whz_h, 0, 1, 2, 3, 4, 5, 6, 7);
    f16x8 AzL = __builtin_shufflevector(wiz_l, whz_l, 0, 1, 2, 3, 4, 5, 6, 7);
    f16x8 Anx = __builtin_shufflevector(win_h, win_l, 0, 1, 2, 3, 4, 5, 6, 7);
    f16x8 Anh = __builtin_shufflevector(whn_h, whn_l, 0, 1, 2, 3, 4, 5, 6, 7);
    const f32x4 br4  = ld4(&bih[4 * hi])      + ld4(&bhh[4 * hi]);
    const f32x4 bz4  = ld4(&bih[16 + 4 * hi]) + ld4(&bhh[16 + 4 * hi]);
    const f32x4 bxn4 = ld4(&bih[32 + 4 * hi]);
    const f32x4 bhn4 = ld4(&bhh[32 + 4 * hi]);

    f32x4 h = {0.f, 0.f, 0.f, 0.f}, hsum = {0.f, 0.f, 0.f, 0.f};
    f16x4 hh = {}, hl = {};

    __syncthreads();   // ids ready; all prologue VMEM drained here

    const int T1 = T - 1;
    const unsigned* idsrow = &s_ids[wid][s * 67];
    float* stg = &s_stage[wid][0][0];
    const int l4 = lane * 4;

#define GADDR(pk) ((hi < 3) \
    ? (const char*)item_table + (size_t)((pk) & 0xffffu) * 48u + hi * 16 \
    : (const char*)cat_table  + (size_t)((pk) >> 16) * 16u)

    // prologue: stage slots 0..3; land 0,1; read e0 into regs
    {
        unsigned p0 = idsrow[0];
        unsigned p1 = idsrow[(1 > T1) ? T1 : 1];
        unsigned p2 = idsrow[(2 > T1) ? T1 : 2];
        unsigned p3 = idsrow[(3 > T1) ? T1 : 3];
        GLDS16(GADDR(p0), stg);
        GLDS16(GADDR(p1), stg + 256);
        GLDS16(GADDR(p2), stg + 512);
        GLDS16(GADDR(p3), stg + 768);
    }
    unsigned idcdA = idsrow[(4 > T1) ? T1 : 4];
    asm volatile("s_waitcnt vmcnt(2)" ::: "memory");
    f32x4 eCur = ld4(stg + l4);

    for (int t = 0; t < T; ++t) {
        // slot t+1 landed (its glds is 2 behind the newest)
        asm volatile("s_waitcnt vmcnt(2)" ::: "memory");
        f32x4 eNext = ld4(stg + (((t + 1) & 3) << 8) + l4);   // for next step
        int t5 = (t + 5 > T1) ? T1 : t + 5;
        unsigned idcdB = idsrow[t5];

        gru_step_mf(eCur, Ar, ArL, Az, AzL, Anx, Anh, win_h, whn_h,
                    br4, bz4, bxn4, bhn4, h, hsum, hh, hl);

        // all DS ops (incl. last step's read of slot t&3) retired — free by now
        asm volatile("s_waitcnt lgkmcnt(0)" ::: "memory");
        GLDS16(GADDR(idcdA), stg + ((t & 3) << 8));           // stage t+4
        idcdA = idcdB;
        eCur  = eNext;
    }

    // ---- epilogue: degenerate MHA -> A[b], all_enc row, BN1 stats ----
    const float* itr = item_table + (size_t)ti * 12;
    f32x4 tv0 = ld4(itr), tv1 = ld4(itr + 4), tv2 = ld4(itr + 8);
    f32x4 tv3 = ld4(cat_table + tc * 4);

    f32x4 vq;
#pragma unroll
    for (int q = 0; q < 4; ++q) {
        int row = 32 + 4 * hi + q;
        const float* wv = mha_Win + row * 16;
        vq[q] = mha_bin[row] + dot4(ld4(wv), tv0) + dot4(ld4(wv + 4), tv1)
              + dot4(ld4(wv + 8), tv2) + dot4(ld4(wv + 12), tv3);
    }
    f32x4 vg0, vg1, vg2, vg3;
#pragma unroll
    for (int q = 0; q < 4; ++q) {
        vg0[q] = __shfl_xor(vq[q], (hi ^ 0) << 4);
        vg1[q] = __shfl_xor(vq[q], (hi ^ 1) << 4);
        vg2[q] = __shfl_xor(vq[q], (hi ^ 2) << 4);
        vg3[q] = __shfl_xor(vq[q], (hi ^ 3) << 4);
    }
    f32x4 aj;
#pragma unroll
    for (int q = 0; q < 4; ++q) {
        int row = 4 * hi + q;
        const float* wo = mha_Wout + row * 16;
        aj[q] = mha_bout[row] + dot4(ld4(wo), vg0) + dot4(ld4(wo + 4), vg1)
              + dot4(ld4(wo + 8), vg2) + dot4(ld4(wo + 12), vg3);
    }
    f32x4 avg = aj * hsum;

    f32x4 u4  = ld4(user_table + (size_t)uid * 16 + 4 * hi);
    f32x4 t4v = (hi == 0) ? tv0 : (hi == 1) ? tv1 : (hi == 2) ? tv2 : tv3;

    if (act) {
        float* er = all_enc + b * 48 + 4 * hi;
        *(f32x4*)er        = avg;
        *(f32x4*)(er + 16) = t4v;
        *(f32x4*)(er + 32) = u4;
    }

    const f32x4 zero4 = {0.f, 0.f, 0.f, 0.f};
    f32x4 sa = act ? avg : zero4, st = act ? t4v : zero4, su = act ? u4 : zero4;
    f32x4 qa = sa * sa, qt = st * st, qu = su * su;
#pragma unroll
    for (int m = 1; m <= 8; m <<= 1) {
#pragma unroll
        for (int q = 0; q < 4; ++q) {
            sa[q] += __shfl_xor(sa[q], m);
            st[q] += __shfl_xor(st[q], m);
            su[q] += __shfl_xor(su[q], m);
            qa[q] += __shfl_xor(qa[q], m);
            qt[q] += __shfl_xor(qt[q], m);
            qu[q] += __shfl_xor(qu[q], m);
        }
    }
    if (s == 0) {
        int c = 4 * hi;
#pragma unroll
        for (int q = 0; q < 4; ++q) {
            lds_part[wid][c + q]      = sa[q];
            lds_part[wid][16 + c + q] = st[q];
            lds_part[wid][32 + c + q] = su[q];
            lds_part[wid][48 + c + q] = qa[q];
            lds_part[wid][64 + c + q] = qt[q];
            lds_part[wid][80 + c + q] = qu[q];
        }
    }
    __syncthreads();
    if (tid < 96) {
        float v = lds_part[0][tid] + lds_part[1][tid] + lds_part[2][tid] + lds_part[3][tid];
        atomicAdd(&stats1[tid], v);
    }
}

// ---------------------------------------------------------------------------
// K3: fc1 with BN1-fold computed inline per block.
// ---------------------------------------------------------------------------
__global__ __launch_bounds__(256) void k_fc1(
    const float* __restrict__ all_enc, const float* __restrict__ stats,
    fp fc1_W, fp fc1_b, fp g1, fp b1,
    float* __restrict__ hbuf, float* __restrict__ stats2, int B)
{
    const int tid = threadIdx.x, lane = tid & 63, wid = tid >> 6;
    const int j = lane & 15, sl = lane >> 4;
    __shared__ float kk[48], mm[48];
    __shared__ float part[4][32];

    if (tid < 48) {
        float mu  = stats[tid] / (float)B;
        float var = stats[48 + tid] / (float)B - mu * mu;
        float k   = rsqrtf(var + BN_EPS);
        float gk  = g1[tid] * k;
        kk[tid] = gk;
        mm[tid] = b1[tid] - mu * gk;
    }
    __syncthreads();

    float w[48];
    float bj = fc1_b[j];
#pragma unroll
    for (int q = 0; q < 12; ++q) {
        float4 v = *(const float4*)&fc1_W[j * 48 + q * 4];
        w[q * 4 + 0] = v.x * kk[q * 4 + 0];
        w[q * 4 + 1] = v.y * kk[q * 4 + 1];
        w[q * 4 + 2] = v.z * kk[q * 4 + 2];
        w[q * 4 + 3] = v.w * kk[q * 4 + 3];
        bj += v.x * mm[q * 4 + 0] + v.y * mm[q * 4 + 1]
            + v.z * mm[q * 4 + 2] + v.w * mm[q * 4 + 3];
    }

    float sh = 0.f, sq = 0.f;
    for (long b = (long)blockIdx.x * 16 + wid * 4 + sl; b < B; b += (long)gridDim.x * 16) {
        const float* x = all_enc + b * 48;
        float acc = bj;
#pragma unroll
        for (int q = 0; q < 12; ++q) {
            float4 v = *(const float4*)&x[q * 4];
            acc += w[q * 4] * v.x + w[q * 4 + 1] * v.y + w[q * 4 + 2] * v.z + w[q * 4 + 3] * v.w;
        }
        float h = fmaxf(acc, 0.f);
        hbuf[b * 16 + j] = h;
        sh += h; sq += h * h;
    }
    sh += __shfl_xor(sh, 16); sh += __shfl_xor(sh, 32);
    sq += __shfl_xor(sq, 16); sq += __shfl_xor(sq, 32);
    if (sl == 0) { part[wid][j] = sh; part[wid][16 + j] = sq; }
    __syncthreads();
    if (tid < 32) {
        float v = part[0][tid] + part[1][tid] + part[2][tid] + part[3][tid];
        atomicAdd(&stats2[tid], v);
    }
}

// ---------------------------------------------------------------------------
// K4: logits + softmax, BN2-fold computed inline per block.
// ---------------------------------------------------------------------------
__global__ __launch_bounds__(256) void k_out(
    const float* __restrict__ hbuf, const float* __restrict__ stats2,
    fp fc2_W, fp fc2_b, fp g2, fp b2, float* __restrict__ out, int B)
{
    __shared__ float w[34];
    const int tid = threadIdx.x;
    if (tid < 32) {
        int c = tid & 15;
        float mu  = stats2[c] / (float)B;
        float var = stats2[16 + c] / (float)B - mu * mu;
        float gk  = g2[c] * rsqrtf(var + BN_EPS);
        w[tid] = fc2_W[tid] * gk;
    }
    if (tid < 2) {
        float acc = fc2_b[tid];
        for (int c = 0; c < 16; ++c) {
            float mu  = stats2[c] / (float)B;
            float var = stats2[16 + c] / (float)B - mu * mu;
            float gk  = g2[c] * rsqrtf(var + BN_EPS);
            acc += fc2_W[tid * 16 + c] * (b2[c] - mu * gk);
        }
        w[32 + tid] = acc;
    }
    __syncthreads();
    for (long b = (long)blockIdx.x * blockDim.x + threadIdx.x; b < B;
         b += (long)gridDim.x * blockDim.x) {
        const float* h = hbuf + b * 16;
        float l0 = w[32], l1 = w[33];
#pragma unroll
        for (int q = 0; q < 4; ++q) {
            float4 v = *(const float4*)&h[q * 4];
            l0 += w[q * 4] * v.x + w[q * 4 + 1] * v.y + w[q * 4 + 2] * v.z + w[q * 4 + 3] * v.w;
            l1 += w[16 + q * 4] * v.x + w[17 + q * 4] * v.y + w[18 + q * 4] * v.z + w[19 + q * 4] * v.w;
        }
        float m  = fmaxf(l0, l1);
        float e0 = __expf(l0 - m), e1 = __expf(l1 - m);
        float inv = frcp(e0 + e1);
        float2 p; p.x = e0 * inv; p.y = e1 * inv;
        *(float2*)&out[b * 2] = p;
    }
}

// ---------------------------------------------------------------------------
extern "C" void kernel_launch(void* const* d_in, const int* in_sizes, int n_in,
                              void* d_out, int out_size, void* d_ws, size_t ws_size,
                              hipStream_t stream)
{
    const int* user_id   = (const int*)d_in[0];
    const int* hist_item = (const int*)d_in[1];
    const int* hist_cat  = (const int*)d_in[2];
    const int* tgt_item  = (const int*)d_in[3];
    const int* tgt_cat   = (const int*)d_in[4];
    fp user_table = (fp)d_in[5];
    fp item_table = (fp)d_in[6];
    fp cat_table  = (fp)d_in[7];
    fp Wih = (fp)d_in[8],  Whh = (fp)d_in[9];
    fp bih = (fp)d_in[10], bhh = (fp)d_in[11];
    fp Win = (fp)d_in[12], binp = (fp)d_in[13];
    fp Wout = (fp)d_in[14], bout = (fp)d_in[15];
    fp g1 = (fp)d_in[16], b1 = (fp)d_in[17];
    fp fc1W = (fp)d_in[18], fc1b = (fp)d_in[19];
    fp g2 = (fp)d_in[20], b2 = (fp)d_in[21];
    fp fc2W = (fp)d_in[22], fc2b = (fp)d_in[23];

    const int B = in_sizes[0];
    const int T = in_sizes[1] / B;

    float* ws      = (float*)d_ws;
    float* stats   = ws;                              // 128 (BN1 96 + BN2 32)
    float* stats2  = stats + 96;
    float* all_enc = stats + 128;                     // B*48
    float* hbuf    = all_enc + (size_t)B * 48;        // B*16

    hipLaunchKernelGGL(k_zero, dim3(1), dim3(128), 0, stream, stats);

    hipLaunchKernelGGL(k_gru, dim3((B + 63) / 64), dim3(256), 0, stream,
                       user_id, hist_item, hist_cat, tgt_item, tgt_cat,
                       user_table, item_table, cat_table, Whh, bhh, Wih, bih,
                       Win, binp, Wout, bout, all_enc, stats, B, T);

    hipLaunchKernelGGL(k_fc1, dim3(512), dim3(256), 0, stream,
                       all_enc, stats, fc1W, fc1b, g1, b1, hbuf, stats2, B);

    hipLaunchKernelGGL(k_out, dim3((B + 255) / 256), dim3(256), 0, stream,
                       hbuf, stats2, fc2W, fc2b, g2, b2, (float*)d_out, B);
}

// Round 8
// 68.350 us; speedup vs baseline: 1.3149x; 1.0951x over previous
//
#include <hip/hip_runtime.h>

#define BN_EPS 1e-5f

typedef const float* fp;
typedef float f32x4 __attribute__((ext_vector_type(4)));
typedef _Float16 f16x2 __attribute__((ext_vector_type(2)));
typedef _Float16 f16x4 __attribute__((ext_vector_type(4)));
typedef _Float16 f16x8 __attribute__((ext_vector_type(8)));

// fast transcendentals: identical formulas to the previous (passing) kernel.
__device__ __forceinline__ float frcp(float x) { return __builtin_amdgcn_rcpf(x); }
__device__ __forceinline__ float sigm(float x) { return frcp(1.0f + __expf(-x)); }
__device__ __forceinline__ float tanh_fast(float x) { return 1.0f - 2.0f * frcp(1.0f + __expf(2.0f * x)); }

__device__ __forceinline__ f32x4 ld4(const float* p) { return *(const f32x4*)p; }
__device__ __forceinline__ float dot4(f32x4 a, f32x4 b) {
    return a[0] * b[0] + a[1] * b[1] + a[2] * b[2] + a[3] * b[3];
}

#define MFMA32(A, B, C) __builtin_amdgcn_mfma_f32_16x16x32_f16((A), (B), (C), 0, 0, 0)

// async global->LDS, 16B per lane; dest = uniform base + lane*16 (HW rule).
#define GLDS16(gp, lp) __builtin_amdgcn_global_load_lds( \
    (const __attribute__((address_space(1))) void*)(gp), \
    (__attribute__((address_space(3))) void*)(lp), 16, 0, 0)

// pack f32x4 -> f16x4 via v_cvt_pkrtz (2 inst).
__device__ __forceinline__ f16x4 pk_f16(f32x4 v) {
    f16x2 lo = __builtin_bit_cast(f16x2, __builtin_amdgcn_cvt_pkrtz(v[0], v[1]));
    f16x2 hi = __builtin_bit_cast(f16x2, __builtin_amdgcn_cvt_pkrtz(v[2], v[3]));
    return __builtin_shufflevector(lo, hi, 0, 1, 2, 3);
}

// ---------------------------------------------------------------------------
// K0: zero the BN stats accumulators.
// ---------------------------------------------------------------------------
__global__ void k_zero(float* __restrict__ stats) { stats[threadIdx.x] = 0.f; }

// ---------------------------------------------------------------------------
// K2: MFMA GRU, 16 samples/wave. Lane l: s=l&15, hi=l>>4.
// B-fragment k=0..15 = [item_emb(12) | cat_emb(4)] (hi==3 lanes gather from
// cat_table), gate biases are constant C-registers. 2-term f16 split: weights
// carry their lo in the A fragment ([W_hi|W_lo] x [act_hi|act_hi], plus the
// [Wih_hi|Whh_hi] x [e_hi|h_hi] main term) — activation-lo dropped (error
// ~1e-4, far under the ~4e-3 transcendental error floor; absmax must stay
// 0.00390625). 6 MFMAs/step, C-chained (no merge adds). Per step:
// vmcnt(2) -> lgkmcnt(0) (free) -> glds(t+4) -> ds_read eNext -> compute.
// D layout == next B layout: zero cross-lane traffic in the recurrence.
// ---------------------------------------------------------------------------
__device__ __forceinline__ void gru_step_mf(
    f32x4 e4,
    const f16x8& Ar, const f16x8& ArL, const f16x8& Az, const f16x8& AzL,
    const f16x8& Anx, const f16x8& Anh,
    const f32x4& br4, const f32x4& bz4, const f32x4& bxn4, const f32x4& bhn4,
    f32x4& h, f32x4& hsum, f16x4& hh)
{
    f16x4 e_h = pk_f16(e4);
    f16x8 Bhh = __builtin_shufflevector(e_h, hh, 0, 1, 2, 3, 4, 5, 6, 7);
    f16x8 Bee = __builtin_shufflevector(e_h, e_h, 0, 1, 2, 3, 0, 1, 2, 3);
    f16x8 Bh2 = __builtin_shufflevector(hh, hh, 0, 1, 2, 3, 0, 1, 2, 3);
    // 4 independent chains; r,z are 2-deep C-chains (no VALU merge adds)
    f32x4 aR = MFMA32(Ar, Bhh, MFMA32(ArL, Bhh, br4));
    f32x4 aZ = MFMA32(Az, Bhh, MFMA32(AzL, Bhh, bz4));
    f32x4 xn = MFMA32(Anx, Bee, bxn4);
    f32x4 hn = MFMA32(Anh, Bh2, bhn4);
    f32x4 r, z, nv;
#pragma unroll
    for (int q = 0; q < 4; ++q) { r[q] = sigm(aR[q]); z[q] = sigm(aZ[q]); }
    f32x4 pre = r * hn + xn;          // vector fma -> v_pk_fma_f32
#pragma unroll
    for (int q = 0; q < 4; ++q) nv[q] = tanh_fast(pre[q]);
    h = z * (h - nv) + nv;            // packed f32 ops
    hsum += h;
    hh = pk_f16(h);
}

__global__ __launch_bounds__(256, 2) void k_gru(
    const int* __restrict__ user_id, const int* __restrict__ hist_item,
    const int* __restrict__ hist_cat, const int* __restrict__ tgt_item,
    const int* __restrict__ tgt_cat,
    fp user_table, fp item_table, fp cat_table,
    fp Whh, fp bhh, fp Wih, fp bih,
    fp mha_Win, fp mha_bin, fp mha_Wout, fp mha_bout,
    float* __restrict__ all_enc, float* __restrict__ stats1, int B, int T)
{
    __shared__ float    s_stage[4][4][256];   // 16KB [wave][slot][lane*4]
    __shared__ unsigned s_ids[4][16 * 67];    // packed (cd<<16)|id, stride 67
    __shared__ float    lds_part[4][96];

    const int tid  = threadIdx.x;
    const int lane = tid & 63;
    const int wid  = tid >> 6;
    const int s    = lane & 15;
    const int hi   = lane >> 4;

    long b = (long)blockIdx.x * 64 + wid * 16 + s;
    const bool act = (b < B);
    if (!act) b = B - 1;

    // epilogue indices: materialize before the barrier (VMEM retires there)
    const int ti  = tgt_item[b];
    const int tc  = tgt_cat[b];
    const int uid = user_id[b];
    asm volatile("" :: "v"(ti), "v"(tc), "v"(uid));

    // one-time packed id preload into LDS
    {
        const int* ip = hist_item + b * T;
        const int* cp = hist_cat  + b * T;
        unsigned* d = &s_ids[wid][s * 67];
        for (int k = hi; k < T; k += 4)
            d[k] = (unsigned)ip[k] | ((unsigned)cp[k] << 16);
    }

    // ---- weight fragments + constant gate biases (one-time) ----
    f32x4 wirf = ld4(&Wih[(0  + s) * 16 + 4 * hi]);
    f32x4 wizf = ld4(&Wih[(16 + s) * 16 + 4 * hi]);
    f32x4 winf = ld4(&Wih[(32 + s) * 16 + 4 * hi]);
    f32x4 whrf = ld4(&Whh[(0  + s) * 16 + 4 * hi]);
    f32x4 whzf = ld4(&Whh[(16 + s) * 16 + 4 * hi]);
    f32x4 whnf = ld4(&Whh[(32 + s) * 16 + 4 * hi]);
    f16x4 wir_h = __builtin_convertvector(wirf, f16x4);
    f16x4 wiz_h = __builtin_convertvector(wizf, f16x4);
    f16x4 win_h = __builtin_convertvector(winf, f16x4);
    f16x4 whr_h = __builtin_convertvector(whrf, f16x4);
    f16x4 whz_h = __builtin_convertvector(whzf, f16x4);
    f16x4 whn_h = __builtin_convertvector(whnf, f16x4);
    f16x4 wir_l = __builtin_convertvector(wirf - __builtin_convertvector(wir_h, f32x4), f16x4);
    f16x4 wiz_l = __builtin_convertvector(wizf - __builtin_convertvector(wiz_h, f32x4), f16x4);
    f16x4 win_l = __builtin_convertvector(winf - __builtin_convertvector(win_h, f32x4), f16x4);
    f16x4 whr_l = __builtin_convertvector(whrf - __builtin_convertvector(whr_h, f32x4), f16x4);
    f16x4 whz_l = __builtin_convertvector(whzf - __builtin_convertvector(whz_h, f32x4), f16x4);
    f16x4 whn_l = __builtin_convertvector(whnf - __builtin_convertvector(whn_h, f32x4), f16x4);
    f16x8 Ar  = __builtin_shufflevector(wir_h, whr_h, 0, 1, 2, 3, 4, 5, 6, 7);
    f16x8 ArL = __builtin_shufflevector(wir_l, whr_l, 0, 1, 2, 3, 4, 5, 6, 7);
    f16x8 Az  = __builtin_shufflevector(wiz_h, whz_h, 0, 1, 2, 3, 4, 5, 6, 7);
    f16x8 AzL = __builtin_shufflevector(wiz_l, whz_l, 0, 1, 2, 3, 4, 5, 6, 7);
    f16x8 Anx = __builtin_shufflevector(win_h, win_l, 0, 1, 2, 3, 4, 5, 6, 7);
    f16x8 Anh = __builtin_shufflevector(whn_h, whn_l, 0, 1, 2, 3, 4, 5, 6, 7);
    const f32x4 br4  = ld4(&bih[4 * hi])      + ld4(&bhh[4 * hi]);
    const f32x4 bz4  = ld4(&bih[16 + 4 * hi]) + ld4(&bhh[16 + 4 * hi]);
    const f32x4 bxn4 = ld4(&bih[32 + 4 * hi]);
    const f32x4 bhn4 = ld4(&bhh[32 + 4 * hi]);

    f32x4 h = {0.f, 0.f, 0.f, 0.f}, hsum = {0.f, 0.f, 0.f, 0.f};
    f16x4 hh = {};

    __syncthreads();   // ids ready; all prologue VMEM drained here

    const int T1 = T - 1;
    const unsigned* idsrow = &s_ids[wid][s * 67];
    float* stg = &s_stage[wid][0][0];
    const int l4 = lane * 4;

#define GADDR(pk) ((hi < 3) \
    ? (const char*)item_table + (size_t)((pk) & 0xffffu) * 48u + hi * 16 \
    : (const char*)cat_table  + (size_t)((pk) >> 16) * 16u)

    // prologue: stage slots 0..3; land 0,1; read e0 into regs
    {
        unsigned p0 = idsrow[0];
        unsigned p1 = idsrow[(1 > T1) ? T1 : 1];
        unsigned p2 = idsrow[(2 > T1) ? T1 : 2];
        unsigned p3 = idsrow[(3 > T1) ? T1 : 3];
        GLDS16(GADDR(p0), stg);
        GLDS16(GADDR(p1), stg + 256);
        GLDS16(GADDR(p2), stg + 512);
        GLDS16(GADDR(p3), stg + 768);
    }
    unsigned idcdA = idsrow[(4 > T1) ? T1 : 4];
    asm volatile("s_waitcnt vmcnt(2)" ::: "memory");
    f32x4 eCur = ld4(stg + l4);

    for (int t = 0; t < T; ++t) {
        // slot t+1 landed (its glds is 3 behind, allowed outstanding = 2)
        asm volatile("s_waitcnt vmcnt(2)" ::: "memory");
        // previous iteration's DS ops are long retired — this is free, and it
        // clears the WAR hazard for re-targeting slot t&3.
        asm volatile("s_waitcnt lgkmcnt(0)" ::: "memory");
        GLDS16(GADDR(idcdA), stg + ((t & 3) << 8));           // stage t+4
        f32x4 eNext = ld4(stg + (((t + 1) & 3) << 8) + l4);   // for next step
        int t5 = (t + 5 > T1) ? T1 : t + 5;
        unsigned idcdB = idsrow[t5];

        gru_step_mf(eCur, Ar, ArL, Az, AzL, Anx, Anh,
                    br4, bz4, bxn4, bhn4, h, hsum, hh);

        idcdA = idcdB;
        eCur  = eNext;
    }

    // ---- epilogue: degenerate MHA -> A[b], all_enc row, BN1 stats ----
    const float* itr = item_table + (size_t)ti * 12;
    f32x4 tv0 = ld4(itr), tv1 = ld4(itr + 4), tv2 = ld4(itr + 8);
    f32x4 tv3 = ld4(cat_table + tc * 4);

    f32x4 vq;
#pragma unroll
    for (int q = 0; q < 4; ++q) {
        int row = 32 + 4 * hi + q;
        const float* wv = mha_Win + row * 16;
        vq[q] = mha_bin[row] + dot4(ld4(wv), tv0) + dot4(ld4(wv + 4), tv1)
              + dot4(ld4(wv + 8), tv2) + dot4(ld4(wv + 12), tv3);
    }
    f32x4 vg0, vg1, vg2, vg3;
#pragma unroll
    for (int q = 0; q < 4; ++q) {
        vg0[q] = __shfl_xor(vq[q], (hi ^ 0) << 4);
        vg1[q] = __shfl_xor(vq[q], (hi ^ 1) << 4);
        vg2[q] = __shfl_xor(vq[q], (hi ^ 2) << 4);
        vg3[q] = __shfl_xor(vq[q], (hi ^ 3) << 4);
    }
    f32x4 aj;
#pragma unroll
    for (int q = 0; q < 4; ++q) {
        int row = 4 * hi + q;
        const float* wo = mha_Wout + row * 16;
        aj[q] = mha_bout[row] + dot4(ld4(wo), vg0) + dot4(ld4(wo + 4), vg1)
              + dot4(ld4(wo + 8), vg2) + dot4(ld4(wo + 12), vg3);
    }
    f32x4 avg = aj * hsum;

    f32x4 u4  = ld4(user_table + (size_t)uid * 16 + 4 * hi);
    f32x4 t4v = (hi == 0) ? tv0 : (hi == 1) ? tv1 : (hi == 2) ? tv2 : tv3;

    if (act) {
        float* er = all_enc + b * 48 + 4 * hi;
        *(f32x4*)er        = avg;
        *(f32x4*)(er + 16) = t4v;
        *(f32x4*)(er + 32) = u4;
    }

    const f32x4 zero4 = {0.f, 0.f, 0.f, 0.f};
    f32x4 sa = act ? avg : zero4, st = act ? t4v : zero4, su = act ? u4 : zero4;
    f32x4 qa = sa * sa, qt = st * st, qu = su * su;
#pragma unroll
    for (int m = 1; m <= 8; m <<= 1) {
#pragma unroll
        for (int q = 0; q < 4; ++q) {
            sa[q] += __shfl_xor(sa[q], m);
            st[q] += __shfl_xor(st[q], m);
            su[q] += __shfl_xor(su[q], m);
            qa[q] += __shfl_xor(qa[q], m);
            qt[q] += __shfl_xor(qt[q], m);
            qu[q] += __shfl_xor(qu[q], m);
        }
    }
    if (s == 0) {
        int c = 4 * hi;
#pragma unroll
        for (int q = 0; q < 4; ++q) {
            lds_part[wid][c + q]      = sa[q];
            lds_part[wid][16 + c + q] = st[q];
            lds_part[wid][32 + c + q] = su[q];
            lds_part[wid][48 + c + q] = qa[q];
            lds_part[wid][64 + c + q] = qt[q];
            lds_part[wid][80 + c + q] = qu[q];
        }
    }
    __syncthreads();
    if (tid < 96) {
        float v = lds_part[0][tid] + lds_part[1][tid] + lds_part[2][tid] + lds_part[3][tid];
        atomicAdd(&stats1[tid], v);
    }
}

// ---------------------------------------------------------------------------
// K3: fc1 with BN1-fold computed inline per block.
// ---------------------------------------------------------------------------
__global__ __launch_bounds__(256) void k_fc1(
    const float* __restrict__ all_enc, const float* __restrict__ stats,
    fp fc1_W, fp fc1_b, fp g1, fp b1,
    float* __restrict__ hbuf, float* __restrict__ stats2, int B)
{
    const int tid = threadIdx.x, lane = tid & 63, wid = tid >> 6;
    const int j = lane & 15, sl = lane >> 4;
    __shared__ float kk[48], mm[48];
    __shared__ float part[4][32];

    if (tid < 48) {
        float mu  = stats[tid] / (float)B;
        float var = stats[48 + tid] / (float)B - mu * mu;
        float k   = rsqrtf(var + BN_EPS);
        float gk  = g1[tid] * k;
        kk[tid] = gk;
        mm[tid] = b1[tid] - mu * gk;
    }
    __syncthreads();

    float w[48];
    float bj = fc1_b[j];
#pragma unroll
    for (int q = 0; q < 12; ++q) {
        float4 v = *(const float4*)&fc1_W[j * 48 + q * 4];
        w[q * 4 + 0] = v.x * kk[q * 4 + 0];
        w[q * 4 + 1] = v.y * kk[q * 4 + 1];
        w[q * 4 + 2] = v.z * kk[q * 4 + 2];
        w[q * 4 + 3] = v.w * kk[q * 4 + 3];
        bj += v.x * mm[q * 4 + 0] + v.y * mm[q * 4 + 1]
            + v.z * mm[q * 4 + 2] + v.w * mm[q * 4 + 3];
    }

    float sh = 0.f, sq = 0.f;
    for (long b = (long)blockIdx.x * 16 + wid * 4 + sl; b < B; b += (long)gridDim.x * 16) {
        const float* x = all_enc + b * 48;
        float acc = bj;
#pragma unroll
        for (int q = 0; q < 12; ++q) {
            float4 v = *(const float4*)&x[q * 4];
            acc += w[q * 4] * v.x + w[q * 4 + 1] * v.y + w[q * 4 + 2] * v.z + w[q * 4 + 3] * v.w;
        }
        float h = fmaxf(acc, 0.f);
        hbuf[b * 16 + j] = h;
        sh += h; sq += h * h;
    }
    sh += __shfl_xor(sh, 16); sh += __shfl_xor(sh, 32);
    sq += __shfl_xor(sq, 16); sq += __shfl_xor(sq, 32);
    if (sl == 0) { part[wid][j] = sh; part[wid][16 + j] = sq; }
    __syncthreads();
    if (tid < 32) {
        float v = part[0][tid] + part[1][tid] + part[2][tid] + part[3][tid];
        atomicAdd(&stats2[tid], v);
    }
}

// ---------------------------------------------------------------------------
// K4: logits + softmax, BN2-fold computed inline per block.
// ---------------------------------------------------------------------------
__global__ __launch_bounds__(256) void k_out(
    const float* __restrict__ hbuf, const float* __restrict__ stats2,
    fp fc2_W, fp fc2_b, fp g2, fp b2, float* __restrict__ out, int B)
{
    __shared__ float w[34];
    const int tid = threadIdx.x;
    if (tid < 32) {
        int c = tid & 15;
        float mu  = stats2[c] / (float)B;
        float var = stats2[16 + c] / (float)B - mu * mu;
        float gk  = g2[c] * rsqrtf(var + BN_EPS);
        w[tid] = fc2_W[tid] * gk;
    }
    if (tid < 2) {
        float acc = fc2_b[tid];
        for (int c = 0; c < 16; ++c) {
            float mu  = stats2[c] / (float)B;
            float var = stats2[16 + c] / (float)B - mu * mu;
            float gk  = g2[c] * rsqrtf(var + BN_EPS);
            acc += fc2_W[tid * 16 + c] * (b2[c] - mu * gk);
        }
        w[32 + tid] = acc;
    }
    __syncthreads();
    for (long b = (long)blockIdx.x * blockDim.x + threadIdx.x; b < B;
         b += (long)gridDim.x * blockDim.x) {
        const float* h = hbuf + b * 16;
        float l0 = w[32], l1 = w[33];
#pragma unroll
        for (int q = 0; q < 4; ++q) {
            float4 v = *(const float4*)&h[q * 4];
            l0 += w[q * 4] * v.x + w[q * 4 + 1] * v.y + w[q * 4 + 2] * v.z + w[q * 4 + 3] * v.w;
            l1 += w[16 + q * 4] * v.x + w[17 + q * 4] * v.y + w[18 + q * 4] * v.z + w[19 + q * 4] * v.w;
        }
        float m  = fmaxf(l0, l1);
        float e0 = __expf(l0 - m), e1 = __expf(l1 - m);
        float inv = frcp(e0 + e1);
        float2 p; p.x = e0 * inv; p.y = e1 * inv;
        *(float2*)&out[b * 2] = p;
    }
}

// ---------------------------------------------------------------------------
extern "C" void kernel_launch(void* const* d_in, const int* in_sizes, int n_in,
                              void* d_out, int out_size, void* d_ws, size_t ws_size,
                              hipStream_t stream)
{
    const int* user_id   = (const int*)d_in[0];
    const int* hist_item = (const int*)d_in[1];
    const int* hist_cat  = (const int*)d_in[2];
    const int* tgt_item  = (const int*)d_in[3];
    const int* tgt_cat   = (const int*)d_in[4];
    fp user_table = (fp)d_in[5];
    fp item_table = (fp)d_in[6];
    fp cat_table  = (fp)d_in[7];
    fp Wih = (fp)d_in[8],  Whh = (fp)d_in[9];
    fp bih = (fp)d_in[10], bhh = (fp)d_in[11];
    fp Win = (fp)d_in[12], binp = (fp)d_in[13];
    fp Wout = (fp)d_in[14], bout = (fp)d_in[15];
    fp g1 = (fp)d_in[16], b1 = (fp)d_in[17];
    fp fc1W = (fp)d_in[18], fc1b = (fp)d_in[19];
    fp g2 = (fp)d_in[20], b2 = (fp)d_in[21];
    fp fc2W = (fp)d_in[22], fc2b = (fp)d_in[23];

    const int B = in_sizes[0];
    const int T = in_sizes[1] / B;

    float* ws      = (float*)d_ws;
    float* stats   = ws;                              // 128 (BN1 96 + BN2 32)
    float* stats2  = stats + 96;
    float* all_enc = stats + 128;                     // B*48
    float* hbuf    = all_enc + (size_t)B * 48;        // B*16

    hipLaunchKernelGGL(k_zero, dim3(1), dim3(128), 0, stream, stats);

    hipLaunchKernelGGL(k_gru, dim3((B + 63) / 64), dim3(256), 0, stream,
                       user_id, hist_item, hist_cat, tgt_item, tgt_cat,
                       user_table, item_table, cat_table, Whh, bhh, Wih, bih,
                       Win, binp, Wout, bout, all_enc, stats, B, T);

    hipLaunchKernelGGL(k_fc1, dim3(512), dim3(256), 0, stream,
                       all_enc, stats, fc1W, fc1b, g1, b1, hbuf, stats2, B);

    hipLaunchKernelGGL(k_out, dim3((B + 255) / 256), dim3(256), 0, stream,
                       hbuf, stats2, fc2W, fc2b, g2, b2, (float*)d_out, B);
}